// Round 1
// 377.592 us; speedup vs baseline: 1.1397x; 1.1397x over previous
//
#include <hip/hip_runtime.h>
#include <math.h>

// Problem constants (fixed by setup_inputs): B=4, H=W=896, n_h=n_w=64,
// GS=8, GL=8, LS=16, LL=8, NA=12, ALPHA=0.5
#define HWPIX 802816            // 896*896
#define OUT_IL 9633792          // offset of I_local  (4*3*896*896)
#define OUT_GG 19267584         // offset of G_global
#define OUT_GL 19292160         // offset of G_local
#define OUT_G  19390464         // offset of g

// workspace layout (float offsets)
#define WS_WT4  0               // combined weight, packed [k/4][o][4], 256x640
#define WS_BC   163840          // combined bias, 256
#define WS_POOL 164096          // pooled [b][c][cell], 4*256*256
#define WS_H    426240          // h vector, 4*256
#define WS_GSEM 427264          // g_sem_patch, 4*4096
#define WS_RG   443648          // global grid [b][y][x][z][c], 4*8*8*8*12
#define WS_RL   468224          // local grid  [b][y][x][z][c], 4*16*16*8*12
#define WS_W1T  566528          // guide_w1 packed [k/4][hidden][4], 384*64

// Fast transcendentals: v_log_f32 (log2 semantics) / v_exp_f32 (exp2) via
// the clang AMDGPU builtins — the CUDA-style __exp2f/__log2f names collide
// with glibc math.h under hipcc (round-4 compile failure). The libm
// cbrtf/powf expansions were the round-3 VALU hog.
__device__ __forceinline__ float fast_exp2(float x) {
  return __builtin_amdgcn_exp2f(x);
}
__device__ __forceinline__ float fast_log2(float x) {
  return __builtin_amdgcn_logf(x);  // v_log_f32 = log2(x)
}
__device__ __forceinline__ float srgb_lin(float v) {
  // pow path only selected for v > 0.04045 (argument strictly positive)
  float p = fast_exp2(2.4f * fast_log2((v + 0.055f) * (1.0f / 1.055f)));
  return v > 0.04045f ? p : v * (1.0f / 12.92f);
}
__device__ __forceinline__ float labf(float t) {
  // cbrt path only selected for t > 0.008856; log2(0)=-inf -> exp2 -> 0 is
  // discarded by the select, no NaN (t >= 0 always here).
  float c = fast_exp2((1.0f / 3.0f) * fast_log2(t));
  return t > 0.008856f ? c : 7.787f * t + (4.0f / 29.0f);
}

// ---------------------------------------------------------------------------
// K1: combined weight W[o][k] (k<256: fusion Wa; k>=256: Wb @ dino_proj_w)
// packed as Wt4[(k>>2)*256 + o][k&3]; plus bc[o] = fusion_b + Wb @ dino_b.
// block 641 packs guide_w1 -> w1T4[((k>>2)*64 + h)*4 + (k&3)].
__global__ __launch_bounds__(256) void k_prep(
    const float* __restrict__ fus_w, const float* __restrict__ fus_b,
    const float* __restrict__ dino_w, const float* __restrict__ dino_b,
    const float* __restrict__ gw1, float* __restrict__ Wt4,
    float* __restrict__ bc, float* __restrict__ w1T) {
  if (blockIdx.x == 641) {
    int t = threadIdx.x;
    for (int it = 0; it < 96; ++it) {
      int idx = it * 256 + t;       // idx over 384*64; k = idx>>6, h = idx&63
      int h = idx & 63;
      int k = idx >> 6;
      w1T[((k >> 2) * 64 + h) * 4 + (k & 3)] = gw1[h * 384 + k];
    }
    return;
  }
  if (blockIdx.x == 640) {
    int o = threadIdx.x;
    float acc = fus_b[o];
    for (int m = 0; m < 128; ++m) acc += fus_w[o * 384 + 256 + m] * dino_b[m];
    bc[o] = acc;
    return;
  }
  int idx = blockIdx.x * 256 + threadIdx.x;
  int o = idx / 640;
  int k = idx - o * 640;
  float val;
  if (k < 256) {
    val = fus_w[o * 384 + k];
  } else {
    int d = k - 256;
    float acc = 0.0f;
    for (int m = 0; m < 128; ++m)
      acc += fus_w[o * 384 + 256 + m] * dino_w[m * 384 + d];
    val = acc;
  }
  Wt4[((k >> 2) * 256 + o) * 4 + (k & 3)] = val;
}

// ---------------------------------------------------------------------------
// K2: pooled[b][o][cell] = (W @ sum_{16 px} x)/16 + bc.  Block = (b, i, jg of 4 cells).
__global__ __launch_bounds__(256) void k_fused_pool(
    const float* __restrict__ R, const float* __restrict__ F,
    const float* __restrict__ Wt4, const float* __restrict__ bc,
    float* __restrict__ pooled) {
  int blk = blockIdx.x;
  int b = blk >> 6;
  int i = (blk >> 2) & 15;
  int jg = blk & 3;
  int t = threadIdx.x;
  __shared__ float s[4 * 640];  // [cell][k]
  {  // R part: thread t = channel c, 4 rows x 4 cells of float4
    const float* rb = R + (((b * 256 + t) * 64 + i * 4) * 64) + jg * 16;
    float p0 = 0, p1 = 0, p2 = 0, p3 = 0;
#pragma unroll
    for (int di = 0; di < 4; ++di) {
      const float4* row = (const float4*)(rb + di * 64);
      float4 v0 = row[0], v1 = row[1], v2 = row[2], v3 = row[3];
      p0 += v0.x + v0.y + v0.z + v0.w;
      p1 += v1.x + v1.y + v1.z + v1.w;
      p2 += v2.x + v2.y + v2.z + v2.w;
      p3 += v3.x + v3.y + v3.z + v3.w;
    }
    s[0 * 640 + t] = p0;
    s[1 * 640 + t] = p1;
    s[2 * 640 + t] = p2;
    s[3 * 640 + t] = p3;
  }
  {  // F part: thread t covers k=t and k=t+256 (t<128)
    float a0[4] = {0, 0, 0, 0};
    float a1[4] = {0, 0, 0, 0};
    for (int pix = 0; pix < 16; ++pix) {
      int row = i * 4 + (pix >> 2);
      int pbase = row * 64 + jg * 16 + (pix & 3);
#pragma unroll
      for (int jj = 0; jj < 4; ++jj) {
        const float* fr = F + (size_t)(b * 4096 + pbase + jj * 4) * 384;
        a0[jj] += fr[t];
        if (t < 128) a1[jj] += fr[256 + t];
      }
    }
#pragma unroll
    for (int jj = 0; jj < 4; ++jj) {
      s[jj * 640 + 256 + t] = a0[jj];
      if (t < 128) s[jj * 640 + 512 + t] = a1[jj];
    }
  }
  __syncthreads();
  float acc0 = 0, acc1 = 0, acc2 = 0, acc3 = 0;
  const float4* w4 = (const float4*)Wt4;
  for (int kk = 0; kk < 160; ++kk) {
    float4 wv = w4[kk * 256 + t];
    float4 s0 = *(const float4*)&s[0 * 640 + kk * 4];
    float4 s1 = *(const float4*)&s[1 * 640 + kk * 4];
    float4 s2 = *(const float4*)&s[2 * 640 + kk * 4];
    float4 s3 = *(const float4*)&s[3 * 640 + kk * 4];
    acc0 += wv.x * s0.x + wv.y * s0.y + wv.z * s0.z + wv.w * s0.w;
    acc1 += wv.x * s1.x + wv.y * s1.y + wv.z * s1.z + wv.w * s1.w;
    acc2 += wv.x * s2.x + wv.y * s2.y + wv.z * s2.z + wv.w * s2.w;
    acc3 += wv.x * s3.x + wv.y * s3.y + wv.z * s3.z + wv.w * s3.w;
  }
  float bco = bc[t];
  float* pr = pooled + ((b * 256 + t) * 256) + i * 16 + jg * 4;
  pr[0] = acc0 * (1.0f / 16.0f) + bco;
  pr[1] = acc1 * (1.0f / 16.0f) + bco;
  pr[2] = acc2 * (1.0f / 16.0f) + bco;
  pr[3] = acc3 * (1.0f / 16.0f) + bco;
}

// ---------------------------------------------------------------------------
// K3a: f_gap = mean(pooled); h = relu(g1_w @ f_gap + g1_b). One block per b.
__global__ __launch_bounds__(256) void k_gap(
    const float* __restrict__ pooled, const float* __restrict__ g1_w,
    const float* __restrict__ g1_b, float* __restrict__ hout) {
  int b = blockIdx.x;
  int t = threadIdx.x;
  __shared__ float f[256];
  const float* pr = pooled + (b * 256 + t) * 256;
  float sum = 0.0f;
  for (int cell = 0; cell < 256; ++cell) sum += pr[cell];
  f[t] = sum * (1.0f / 256.0f);
  __syncthreads();
  float acc = g1_b[t];
  const float* wr = g1_w + t * 256;
  for (int k = 0; k < 256; ++k) acc += wr[k] * f[k];
  hout[b * 256 + t] = fmaxf(acc, 0.0f);
}

// ---------------------------------------------------------------------------
// K3b: G_global = h @ g2_w.T + g2_b  (+ slice-layout copy)
__global__ __launch_bounds__(256) void k_gglobal(
    const float* __restrict__ h, const float* __restrict__ g2_w,
    const float* __restrict__ g2_b, float* __restrict__ out3,
    float* __restrict__ rg) {
  int b = blockIdx.x / 24;
  int o = (blockIdx.x % 24) * 256 + threadIdx.x;
  __shared__ float hl[256];
  hl[threadIdx.x] = h[b * 256 + threadIdx.x];
  __syncthreads();
  float acc = g2_b[o];
  const float* wr = g2_w + o * 256;
  for (int k = 0; k < 256; ++k) acc += wr[k] * hl[k];
  out3[b * 6144 + o] = acc;
  int n = o >> 9, y = (o >> 6) & 7, x = (o >> 3) & 7, z = o & 7;
  rg[b * 6144 + ((y * 8 + x) * 8 + z) * 12 + n] = acc;
}

// ---------------------------------------------------------------------------
// K4: G_local = transpose(local_w @ pooled + local_b)  (+ slice-layout copy)
__global__ __launch_bounds__(256) void k_glocal(
    const float* __restrict__ pooled, const float* __restrict__ lw,
    const float* __restrict__ lb, float* __restrict__ out4,
    float* __restrict__ rl) {
  int idx = blockIdx.x * 256 + threadIdx.x;
  int b = idx / 24576;
  int r = idx - b * 24576;
  int o = r >> 8;
  int cell = r & 255;
  float acc = lb[o];
  const float* wr = lw + o * 256;
  const float* pr = pooled + b * 65536 + cell;
  for (int c = 0; c < 256; ++c) acc += wr[c] * pr[c * 256];
  int n = o >> 3, l = o & 7;
  out4[((b * 12 + n) * 256 + cell) * 8 + l] = acc;
  rl[b * 24576 + (cell * 8 + l) * 12 + n] = acc;
}

// ---------------------------------------------------------------------------
// K5: semantic guide. One wave = 8 patches; lane = hidden unit.
// w1T packed [k/4][h][4]: each lane reads its 4 k-values as one float4
// (coalesced, 16B/lane). F rows are wave-uniform float4 broadcast loads.
// K walked in chunks of 8 -> register working set stays ~40 VGPRs (the
// round-2 wreg[64] variant spilled to scratch: 900 MB HBM traffic).
__global__ __launch_bounds__(256) void k_guide(
    const float* __restrict__ F, const float* __restrict__ w1T,
    const float* __restrict__ b1, const float* __restrict__ w2,
    const float* __restrict__ b2, float* __restrict__ gsem) {
  int wave = threadIdx.x >> 6;
  int lane = threadIdx.x & 63;
  int gw = blockIdx.x * 4 + wave;   // 2048 waves
  int p0 = gw * 8;                  // first patch of this wave
  float acc[8];
#pragma unroll
  for (int p = 0; p < 8; ++p) acc[p] = 0.0f;
  const float* fbase = F + (size_t)p0 * 384;
  const float4* w4 = (const float4*)w1T;   // [k/4][64 lanes]
  for (int c = 0; c < 48; ++c) {           // 8 k per chunk
    int k0 = c * 8;
    float4 wa = w4[(c * 2 + 0) * 64 + lane];  // k0..k0+3
    float4 wb = w4[(c * 2 + 1) * 64 + lane];  // k0+4..k0+7
#pragma unroll
    for (int p = 0; p < 8; ++p) {
      const float4* fr = (const float4*)(fbase + (size_t)p * 384 + k0);
      float4 va = fr[0];
      float4 vb = fr[1];
      acc[p] += va.x * wa.x + va.y * wa.y + va.z * wa.z + va.w * wa.w +
                vb.x * wb.x + vb.y * wb.y + vb.z * wb.z + vb.w * wb.w;
    }
  }
  float hb = b1[lane];
  float wl = w2[lane];
  float b2v = b2[0];
  float res = 0.0f;
#pragma unroll
  for (int p = 0; p < 8; ++p) {
    float v = fmaxf(acc[p] + hb, 0.0f) * wl;
#pragma unroll
    for (int m = 32; m >= 1; m >>= 1) v += __shfl_xor(v, m, 64);
    if (lane == p) res = v;   // after butterfly, every lane has the sum
  }
  if (lane < 8) gsem[p0 + lane] = 1.0f / (1.0f + expf(-(res + b2v)));
}

// ---------------------------------------------------------------------------
// K6: per-pixel — one block per image ROW (b,h). Within a row, y0/y1/wy are
// constant for the gsem bilinear AND both bilateral slices, so the
// y-interpolation is hoisted: the two needed grid rows are pre-combined
// into LDS once per block. Per pixel the slice then reads only
// 2x * 2z * 12c from LDS (12 ds_read_b128 per slice vs 24 global float4
// gathers before) — this was the ~52% latency-stall in the 100 us version
// (768 B/pixel of per-lane-divergent L1/L2 gather traffic, VALUBusy 48%,
// HBM 14%). LDS bank math: entry stride is 12 floats, so z in 0..7 maps to
// banks {0,12,24,4,16,28,8,20} — all distinct, conflict-free; same-z lanes
// broadcast.
template <int SDIM>
__device__ __forceinline__ void slice_lds(
    const float* __restrict__ sg, int w, int z0, int z1, float wz,
    float r, float g, float bl, float& o0, float& o1, float& o2) {
  constexpr float sc = (float)(SDIM - 1) * (1.0f / 895.0f);
  float fxs = (float)w * sc;
  int x0 = (int)fxs;
  if (x0 > SDIM - 1) x0 = SDIM - 1;
  int x1 = x0 < SDIM - 1 ? x0 + 1 : SDIM - 1;
  float wx = fxs - (float)x0;
  float wz0 = 1.0f - wz;
  float w00 = (1.0f - wx) * wz0;   // (x0, z0)
  float w01 = (1.0f - wx) * wz;    // (x0, z1)
  float w10 = wx * wz0;            // (x1, z0)
  float w11 = wx * wz;             // (x1, z1)
  const float4* p00 = (const float4*)(sg + (x0 * 8 + z0) * 12);
  const float4* p01 = (const float4*)(sg + (x0 * 8 + z1) * 12);
  const float4* p10 = (const float4*)(sg + (x1 * 8 + z0) * 12);
  const float4* p11 = (const float4*)(sg + (x1 * 8 + z1) * 12);
  float a[12];
#pragma unroll
  for (int c = 0; c < 3; ++c) {
    float4 v00 = p00[c], v01 = p01[c], v10 = p10[c], v11 = p11[c];
    a[4 * c + 0] = w00 * v00.x + w01 * v01.x + w10 * v10.x + w11 * v11.x;
    a[4 * c + 1] = w00 * v00.y + w01 * v01.y + w10 * v10.y + w11 * v11.y;
    a[4 * c + 2] = w00 * v00.z + w01 * v01.z + w10 * v10.z + w11 * v11.z;
    a[4 * c + 3] = w00 * v00.w + w01 * v01.w + w10 * v10.w + w11 * v11.w;
  }
  o0 = fminf(fmaxf(a[0] * r + a[1] * g + a[2] * bl + a[9], 0.0f), 1.0f);
  o1 = fminf(fmaxf(a[3] * r + a[4] * g + a[5] * bl + a[10], 0.0f), 1.0f);
  o2 = fminf(fmaxf(a[6] * r + a[7] * g + a[8] * bl + a[11], 0.0f), 1.0f);
}

// 448 threads = 7 waves; 896 = 2 * 448 so each thread owns exactly 2 pixels
// (no tail divergence). Grid = 4 * 896 rows. LDS: 64 + 768 + 1536 floats
// = 9.25 KB -> occupancy capped by waves (4 blocks = 28 waves/CU).
__global__ __launch_bounds__(448) void k_pixel(
    const float* __restrict__ img, const float* __restrict__ gsem,
    const float* __restrict__ rg, const float* __restrict__ rl,
    float* __restrict__ out) {
  int blk = blockIdx.x;
  int b = blk / 896;
  int h = blk - b * 896;
  int t = threadIdx.x;
  __shared__ float sgr[64];     // y-interp'd gsem row
  __shared__ float sG[768];     // y-interp'd global grid row [x][z][c]
  __shared__ float sL[1536];    // y-interp'd local grid row  [x][z][c]

  // gsem y factors (half-pixel centers, edge clamp)
  float sy = fminf(fmaxf((h + 0.5f) * (1.0f / 14.0f) - 0.5f, 0.0f), 63.0f);
  int y0s = (int)sy;
  int y1s = y0s < 63 ? y0s + 1 : 63;
  float wys = sy - (float)y0s;
  // global slice y factors (linspace 0..S-1 over 896)
  float fyg = (float)h * (7.0f / 895.0f);
  int y0g = (int)fyg;
  if (y0g > 7) y0g = 7;
  int y1g = y0g < 7 ? y0g + 1 : 7;
  float wyg = fyg - (float)y0g;
  // local slice y factors
  float fyl = (float)h * (15.0f / 895.0f);
  int y0l = (int)fyl;
  if (y0l > 15) y0l = 15;
  int y1l = y0l < 15 ? y0l + 1 : 15;
  float wyl = fyl - (float)y0l;

  if (t < 64) {
    const float* gb = gsem + b * 4096;
    sgr[t] = gb[y0s * 64 + t] * (1.0f - wys) + gb[y1s * 64 + t] * wys;
  }
  {
    const float* g0 = rg + b * 6144 + y0g * 768;
    const float* g1 = rg + b * 6144 + y1g * 768;
    for (int i = t; i < 768; i += 448)
      sG[i] = g0[i] * (1.0f - wyg) + g1[i] * wyg;
    const float* l0 = rl + b * 24576 + y0l * 1536;
    const float* l1 = rl + b * 24576 + y1l * 1536;
    for (int i = t; i < 1536; i += 448)
      sL[i] = l0[i] * (1.0f - wyl) + l1[i] * wyl;
  }
  __syncthreads();

#pragma unroll
  for (int ip = 0; ip < 2; ++ip) {
    int w = ip * 448 + t;
    int hw = h * 896 + w;
    float r = img[(b * 3 + 0) * HWPIX + hw];
    float g = img[(b * 3 + 1) * HWPIX + hw];
    float bl = img[(b * 3 + 2) * HWPIX + hw];
    // Lab -> chroma guide (constants folded: (0.5*116 fy - 0.5*16 +
    // 0.25*500|fx-fy| + 0.25*200|fy-fz|)/114)
    float lr = srgb_lin(r), lg = srgb_lin(g), lb2 = srgb_lin(bl);
    float X = 0.412453f * lr + 0.357580f * lg + 0.180423f * lb2;
    float Y = 0.212671f * lr + 0.715160f * lg + 0.072169f * lb2;
    float Z = 0.019334f * lr + 0.119193f * lg + 0.950227f * lb2;
    float fx_ = labf(X * (1.0f / 0.950456f));
    float fy_ = labf(Y);
    float fz_ = labf(Z * (1.0f / 1.088754f));
    float gch = 0.50877193f * fy_ - 0.070175439f +
                1.0964912f * fabsf(fx_ - fy_) + 0.43859649f * fabsf(fy_ - fz_);
    gch = fminf(fmaxf(gch, 0.0f), 1.0f);
    // g_sem bilinear: y already folded into sgr, only x-interp here
    float sx = fminf(fmaxf((w + 0.5f) * (1.0f / 14.0f) - 0.5f, 0.0f), 63.0f);
    int x0s = (int)sx;
    int x1s = x0s < 63 ? x0s + 1 : 63;
    float wxs = sx - (float)x0s;
    float gs = sgr[x0s] * (1.0f - wxs) + sgr[x1s] * wxs;
    float gg = 0.5f * gch + 0.5f * gs;
    __builtin_nontemporal_store(gg, &out[OUT_G + b * HWPIX + hw]);
    // z coordinate shared by both slices (l=8 for both)
    float fzc = fminf(fmaxf(gg * 7.0f, 0.0f), 7.0f);
    int z0 = (int)fzc;
    if (z0 > 7) z0 = 7;
    int z1 = z0 < 7 ? z0 + 1 : 7;
    float wz = fzc - (float)z0;
    float o0, o1, o2;
    slice_lds<8>(sG, w, z0, z1, wz, r, g, bl, o0, o1, o2);
    __builtin_nontemporal_store(o0, &out[(b * 3 + 0) * HWPIX + hw]);
    __builtin_nontemporal_store(o1, &out[(b * 3 + 1) * HWPIX + hw]);
    __builtin_nontemporal_store(o2, &out[(b * 3 + 2) * HWPIX + hw]);
    slice_lds<16>(sL, w, z0, z1, wz, r, g, bl, o0, o1, o2);
    __builtin_nontemporal_store(o0, &out[OUT_IL + (b * 3 + 0) * HWPIX + hw]);
    __builtin_nontemporal_store(o1, &out[OUT_IL + (b * 3 + 1) * HWPIX + hw]);
    __builtin_nontemporal_store(o2, &out[OUT_IL + (b * 3 + 2) * HWPIX + hw]);
  }
}

// ---------------------------------------------------------------------------
extern "C" void kernel_launch(void* const* d_in, const int* in_sizes, int n_in,
                              void* d_out, int out_size, void* d_ws,
                              size_t ws_size, hipStream_t stream) {
  const float* R = (const float*)d_in[0];
  const float* F = (const float*)d_in[1];
  const float* img = (const float*)d_in[2];
  const float* dino_w = (const float*)d_in[5];
  const float* dino_b = (const float*)d_in[6];
  const float* fus_w = (const float*)d_in[7];
  const float* fus_b = (const float*)d_in[8];
  const float* g1_w = (const float*)d_in[9];
  const float* g1_b = (const float*)d_in[10];
  const float* g2_w = (const float*)d_in[11];
  const float* g2_b = (const float*)d_in[12];
  const float* lw = (const float*)d_in[13];
  const float* lb = (const float*)d_in[14];
  const float* gw1 = (const float*)d_in[15];
  const float* gb1 = (const float*)d_in[16];
  const float* gw2 = (const float*)d_in[17];
  const float* gb2 = (const float*)d_in[18];
  float* out = (float*)d_out;
  float* ws = (float*)d_ws;

  float* Wt4 = ws + WS_WT4;
  float* bc = ws + WS_BC;
  float* pooled = ws + WS_POOL;
  float* hbuf = ws + WS_H;
  float* gsem = ws + WS_GSEM;
  float* rg = ws + WS_RG;
  float* rl = ws + WS_RL;
  float* w1T = ws + WS_W1T;

  k_prep<<<642, 256, 0, stream>>>(fus_w, fus_b, dino_w, dino_b, gw1, Wt4, bc, w1T);
  k_guide<<<512, 256, 0, stream>>>(F, w1T, gb1, gw2, gb2, gsem);
  k_fused_pool<<<256, 256, 0, stream>>>(R, F, Wt4, bc, pooled);
  k_gap<<<4, 256, 0, stream>>>(pooled, g1_w, g1_b, hbuf);
  k_gglobal<<<96, 256, 0, stream>>>(hbuf, g2_w, g2_b, out + OUT_GG, rg);
  k_glocal<<<384, 256, 0, stream>>>(pooled, lw, lb, out + OUT_GL, rl);
  k_pixel<<<3584, 448, 0, stream>>>(img, gsem, rg, rl, out);
}

// Round 2
// 324.112 us; speedup vs baseline: 1.3277x; 1.1650x over previous
//
#include <hip/hip_runtime.h>
#include <math.h>

// Problem constants (fixed by setup_inputs): B=4, H=W=896, n_h=n_w=64,
// GS=8, GL=8, LS=16, LL=8, NA=12, ALPHA=0.5
#define HWPIX 802816            // 896*896
#define OUT_IL 9633792          // offset of I_local  (4*3*896*896)
#define OUT_GG 19267584         // offset of G_global
#define OUT_GL 19292160         // offset of G_local
#define OUT_G  19390464         // offset of g

// workspace layout (float offsets)
#define WS_WT4  0               // combined weight, packed [k/4][o][4], 256x640
#define WS_BC   163840          // combined bias, 256
#define WS_POOL 164096          // pooled [b][c][cell], 4*256*256
#define WS_H    426240          // h vector, 4*256
#define WS_GSEM 427264          // g_sem_patch, 4*4096
#define WS_RG   443648          // global grid [b][y][x][z][c], 4*8*8*8*12
#define WS_RL   468224          // local grid  [b][y][x][z][c], 4*16*16*8*12
#define WS_W1T  566528          // guide_w1 packed [k/4][hidden][4], 384*64

// Fast transcendentals: v_log_f32 (log2 semantics) / v_exp_f32 (exp2) via
// the clang AMDGPU builtins — the CUDA-style __exp2f/__log2f names collide
// with glibc math.h under hipcc (round-4 compile failure). The libm
// cbrtf/powf expansions were the round-3 VALU hog.
__device__ __forceinline__ float fast_exp2(float x) {
  return __builtin_amdgcn_exp2f(x);
}
__device__ __forceinline__ float fast_log2(float x) {
  return __builtin_amdgcn_logf(x);  // v_log_f32 = log2(x)
}
__device__ __forceinline__ float srgb_lin(float v) {
  // pow path only selected for v > 0.04045 (argument strictly positive)
  float p = fast_exp2(2.4f * fast_log2((v + 0.055f) * (1.0f / 1.055f)));
  return v > 0.04045f ? p : v * (1.0f / 12.92f);
}
__device__ __forceinline__ float labf(float t) {
  // cbrt path only selected for t > 0.008856; log2(0)=-inf -> exp2 -> 0 is
  // discarded by the select, no NaN (t >= 0 always here).
  float c = fast_exp2((1.0f / 3.0f) * fast_log2(t));
  return t > 0.008856f ? c : 7.787f * t + (4.0f / 29.0f);
}

// ---------------------------------------------------------------------------
// K1: combined weight W[o][k] (k<256: fusion Wa; k>=256: Wb @ dino_proj_w)
// packed as Wt4[(k>>2)*256 + o][k&3]; plus bc[o] = fusion_b + Wb @ dino_b.
// block 641 packs guide_w1 -> w1T4[((k>>2)*64 + h)*4 + (k&3)].
__global__ __launch_bounds__(256) void k_prep(
    const float* __restrict__ fus_w, const float* __restrict__ fus_b,
    const float* __restrict__ dino_w, const float* __restrict__ dino_b,
    const float* __restrict__ gw1, float* __restrict__ Wt4,
    float* __restrict__ bc, float* __restrict__ w1T) {
  if (blockIdx.x == 641) {
    int t = threadIdx.x;
    for (int it = 0; it < 96; ++it) {
      int idx = it * 256 + t;       // idx over 384*64; k = idx>>6, h = idx&63
      int h = idx & 63;
      int k = idx >> 6;
      w1T[((k >> 2) * 64 + h) * 4 + (k & 3)] = gw1[h * 384 + k];
    }
    return;
  }
  if (blockIdx.x == 640) {
    int o = threadIdx.x;
    float acc = fus_b[o];
    for (int m = 0; m < 128; ++m) acc += fus_w[o * 384 + 256 + m] * dino_b[m];
    bc[o] = acc;
    return;
  }
  int idx = blockIdx.x * 256 + threadIdx.x;
  int o = idx / 640;
  int k = idx - o * 640;
  float val;
  if (k < 256) {
    val = fus_w[o * 384 + k];
  } else {
    int d = k - 256;
    float acc = 0.0f;
    for (int m = 0; m < 128; ++m)
      acc += fus_w[o * 384 + 256 + m] * dino_w[m * 384 + d];
    val = acc;
  }
  Wt4[((k >> 2) * 256 + o) * 4 + (k & 3)] = val;
}

// ---------------------------------------------------------------------------
// K2: pooled[b][o][cell] = (W @ sum_{16 px} x)/16 + bc.
// Round-1 rework: was 256 blocks x 256 thr = 1 wave/SIMD (Occupancy 10.5%,
// VALUBusy 9%, HBM 6% -> pure latency exposure at 67 us). Now 1024 threads
// per block (16 waves/CU): thread = (cell, o), 1 accumulator each; staging
// work per thread drops 4x; W traffic per block unchanged (same-o threads
// across cells hit identical lines). Epilogue transposes through LDS so the
// pooled float4 write pattern is preserved.
__global__ __launch_bounds__(1024) void k_fused_pool(
    const float* __restrict__ R, const float* __restrict__ F,
    const float* __restrict__ Wt4, const float* __restrict__ bc,
    float* __restrict__ pooled) {
  int blk = blockIdx.x;
  int b = blk >> 6;
  int i = (blk >> 2) & 15;
  int jg = blk & 3;
  int t = threadIdx.x;
  int cell = t >> 8;        // 0..3
  int c = t & 255;          // channel / output index
  __shared__ float s[4 * 640];  // [cell][k]
  {  // R part: sum 4x4 pixel block of channel c for this cell
    const float* rb = R + (((b * 256 + c) * 64 + i * 4) * 64) + (jg * 4 + cell) * 4;
    float p = 0.0f;
#pragma unroll
    for (int di = 0; di < 4; ++di) {
      float4 v = *(const float4*)(rb + di * 64);
      p += v.x + v.y + v.z + v.w;
    }
    s[cell * 640 + c] = p;
  }
  {  // F part: thread covers k=256+c (and k=512+c for c<128)
    float a0 = 0.0f, a1 = 0.0f;
    const float* fb = F + (size_t)(b * 4096 + (i * 4) * 64 + (jg * 4 + cell) * 4) * 384;
#pragma unroll
    for (int pix = 0; pix < 16; ++pix) {
      const float* fr = fb + (size_t)((pix >> 2) * 64 + (pix & 3)) * 384;
      a0 += fr[c];
      if (c < 128) a1 += fr[256 + c];
    }
    s[cell * 640 + 256 + c] = a0;
    if (c < 128) s[cell * 640 + 512 + c] = a1;
  }
  __syncthreads();
  float acc = 0.0f;
  const float4* w4 = (const float4*)Wt4;
  const float4* s4 = (const float4*)(s + cell * 640);
#pragma unroll 8
  for (int kk = 0; kk < 160; ++kk) {
    float4 wv = w4[kk * 256 + c];
    float4 sv = s4[kk];
    acc += wv.x * sv.x + wv.y * sv.y + wv.z * sv.z + wv.w * sv.w;
  }
  __syncthreads();
  s[cell * 256 + c] = acc;   // reuse staging LDS for the (cell,o) transpose
  __syncthreads();
  if (t < 256) {
    float bco = bc[t];
    float4 v;
    v.x = s[0 * 256 + t] * (1.0f / 16.0f) + bco;
    v.y = s[1 * 256 + t] * (1.0f / 16.0f) + bco;
    v.z = s[2 * 256 + t] * (1.0f / 16.0f) + bco;
    v.w = s[3 * 256 + t] * (1.0f / 16.0f) + bco;
    *(float4*)(pooled + ((size_t)(b * 256 + t) * 256) + i * 16 + jg * 4) = v;
  }
}

// ---------------------------------------------------------------------------
// K3a: f_gap = mean(pooled); h = relu(g1_w @ f_gap + g1_b). One block per b.
// Round-1: 1024 threads, 4-way split over cells (phase 1) and k (phase 2),
// float4 loads — was 4 blocks x 256 scalar-loop threads.
__global__ __launch_bounds__(1024) void k_gap(
    const float* __restrict__ pooled, const float* __restrict__ g1_w,
    const float* __restrict__ g1_b, float* __restrict__ hout) {
  int b = blockIdx.x;
  int t = threadIdx.x;
  int o = t & 255;
  int q = t >> 8;           // 0..3
  __shared__ float f[256];
  __shared__ float part[4][256];
  {  // phase 1: partial sums over 64 cells each
    const float4* pr4 = (const float4*)(pooled + (size_t)(b * 256 + o) * 256 + q * 64);
    float s = 0.0f;
#pragma unroll
    for (int i = 0; i < 16; ++i) {
      float4 v = pr4[i];
      s += v.x + v.y + v.z + v.w;
    }
    part[q][o] = s;
  }
  __syncthreads();
  if (t < 256)
    f[t] = (part[0][t] + part[1][t] + part[2][t] + part[3][t]) * (1.0f / 256.0f);
  __syncthreads();
  {  // phase 2: partial dot over 64 k each
    const float4* wr = (const float4*)(g1_w + o * 256 + q * 64);
    const float4* fq = (const float4*)(f + q * 64);
    float acc = 0.0f;
#pragma unroll
    for (int i = 0; i < 16; ++i) {
      float4 w = wr[i];
      float4 fv = fq[i];
      acc += w.x * fv.x + w.y * fv.y + w.z * fv.z + w.w * fv.w;
    }
    part[q][o] = acc;
  }
  __syncthreads();
  if (t < 256) {
    float a = part[0][t] + part[1][t] + part[2][t] + part[3][t] + g1_b[t];
    hout[b * 256 + t] = fmaxf(a, 0.0f);
  }
}

// ---------------------------------------------------------------------------
// K3b: G_global = h @ g2_w.T + g2_b  (+ slice-layout copy)
__global__ __launch_bounds__(256) void k_gglobal(
    const float* __restrict__ h, const float* __restrict__ g2_w,
    const float* __restrict__ g2_b, float* __restrict__ out3,
    float* __restrict__ rg) {
  int b = blockIdx.x / 24;
  int o = (blockIdx.x % 24) * 256 + threadIdx.x;
  __shared__ float hl[256];
  hl[threadIdx.x] = h[b * 256 + threadIdx.x];
  __syncthreads();
  float acc = g2_b[o];
  const float* wr = g2_w + o * 256;
  for (int k = 0; k < 256; ++k) acc += wr[k] * hl[k];
  out3[b * 6144 + o] = acc;
  int n = o >> 9, y = (o >> 6) & 7, x = (o >> 3) & 7, z = o & 7;
  rg[b * 6144 + ((y * 8 + x) * 8 + z) * 12 + n] = acc;
}

// ---------------------------------------------------------------------------
// K4: G_local = transpose(local_w @ pooled + local_b)  (+ slice-layout copy)
__global__ __launch_bounds__(256) void k_glocal(
    const float* __restrict__ pooled, const float* __restrict__ lw,
    const float* __restrict__ lb, float* __restrict__ out4,
    float* __restrict__ rl) {
  int idx = blockIdx.x * 256 + threadIdx.x;
  int b = idx / 24576;
  int r = idx - b * 24576;
  int o = r >> 8;
  int cell = r & 255;
  float acc = lb[o];
  const float* wr = lw + o * 256;
  const float* pr = pooled + b * 65536 + cell;
  for (int c = 0; c < 256; ++c) acc += wr[c] * pr[c * 256];
  int n = o >> 3, l = o & 7;
  out4[((b * 12 + n) * 256 + cell) * 8 + l] = acc;
  rl[b * 24576 + (cell * 8 + l) * 12 + n] = acc;
}

// ---------------------------------------------------------------------------
// K5: semantic guide. Round-1 rework: was 512 blocks (2 waves/SIMD, 19%
// occupancy) with every F row loaded as a wave-uniform GLOBAL broadcast at
// L3 latency. Now: 1024 blocks of 256 threads; each block stages 16 F rows
// (24 KB) into LDS with coalesced float4 loads; each wave computes 4
// patches (lane = hidden unit) from LDS broadcasts. 4096 waves -> entire
// grid resident, 16 waves/CU.
__global__ __launch_bounds__(256) void k_guide(
    const float* __restrict__ F, const float* __restrict__ w1T,
    const float* __restrict__ b1, const float* __restrict__ w2,
    const float* __restrict__ b2, float* __restrict__ gsem) {
  int t = threadIdx.x;
  int wave = t >> 6;
  int lane = t & 63;
  int pb = blockIdx.x * 16;          // first patch of this block
  __shared__ float4 sF[16 * 96];     // 16 rows x 384 floats
  const float4* Fb = (const float4*)(F + (size_t)pb * 384);
#pragma unroll
  for (int r = 0; r < 6; ++r) sF[r * 256 + t] = Fb[r * 256 + t];
  __syncthreads();
  float accp[4] = {0.0f, 0.0f, 0.0f, 0.0f};
  const float4* w4 = (const float4*)w1T;   // [k/4][64 lanes]
  int prow = wave * 4;               // patch offset within block
  for (int c = 0; c < 48; ++c) {     // 8 k per chunk
    float4 wa = w4[(c * 2 + 0) * 64 + lane];
    float4 wb = w4[(c * 2 + 1) * 64 + lane];
#pragma unroll
    for (int p = 0; p < 4; ++p) {
      float4 va = sF[(prow + p) * 96 + c * 2 + 0];
      float4 vb = sF[(prow + p) * 96 + c * 2 + 1];
      accp[p] += va.x * wa.x + va.y * wa.y + va.z * wa.z + va.w * wa.w +
                 vb.x * wb.x + vb.y * wb.y + vb.z * wb.z + vb.w * wb.w;
    }
  }
  float hb = b1[lane];
  float wl = w2[lane];
  float b2v = b2[0];
  float res = 0.0f;
#pragma unroll
  for (int p = 0; p < 4; ++p) {
    float v = fmaxf(accp[p] + hb, 0.0f) * wl;
#pragma unroll
    for (int m = 32; m >= 1; m >>= 1) v += __shfl_xor(v, m, 64);
    if (lane == p) res = v;   // after butterfly, every lane has the sum
  }
  if (lane < 4) gsem[pb + prow + lane] = 1.0f / (1.0f + expf(-(res + b2v)));
}

// ---------------------------------------------------------------------------
// K6: per-pixel — one block per image ROW (b,h). Within a row, y0/y1/wy are
// constant for the gsem bilinear AND both bilateral slices, so the
// y-interpolation is hoisted: the two needed grid rows are pre-combined
// into LDS once per block. Per pixel the slice then reads only
// 2x * 2z * 12c from LDS (12 ds_read_b128 per slice vs 24 global float4
// gathers before) — this was the ~52% latency-stall in the 100 us version
// (768 B/pixel of per-lane-divergent L1/L2 gather traffic, VALUBusy 48%,
// HBM 14%). LDS bank math: entry stride is 12 floats, so z in 0..7 maps to
// banks {0,12,24,4,16,28,8,20} — all distinct, conflict-free; same-z lanes
// broadcast.
template <int SDIM>
__device__ __forceinline__ void slice_lds(
    const float* __restrict__ sg, int w, int z0, int z1, float wz,
    float r, float g, float bl, float& o0, float& o1, float& o2) {
  constexpr float sc = (float)(SDIM - 1) * (1.0f / 895.0f);
  float fxs = (float)w * sc;
  int x0 = (int)fxs;
  if (x0 > SDIM - 1) x0 = SDIM - 1;
  int x1 = x0 < SDIM - 1 ? x0 + 1 : SDIM - 1;
  float wx = fxs - (float)x0;
  float wz0 = 1.0f - wz;
  float w00 = (1.0f - wx) * wz0;   // (x0, z0)
  float w01 = (1.0f - wx) * wz;    // (x0, z1)
  float w10 = wx * wz0;            // (x1, z0)
  float w11 = wx * wz;             // (x1, z1)
  const float4* p00 = (const float4*)(sg + (x0 * 8 + z0) * 12);
  const float4* p01 = (const float4*)(sg + (x0 * 8 + z1) * 12);
  const float4* p10 = (const float4*)(sg + (x1 * 8 + z0) * 12);
  const float4* p11 = (const float4*)(sg + (x1 * 8 + z1) * 12);
  float a[12];
#pragma unroll
  for (int c = 0; c < 3; ++c) {
    float4 v00 = p00[c], v01 = p01[c], v10 = p10[c], v11 = p11[c];
    a[4 * c + 0] = w00 * v00.x + w01 * v01.x + w10 * v10.x + w11 * v11.x;
    a[4 * c + 1] = w00 * v00.y + w01 * v01.y + w10 * v10.y + w11 * v11.y;
    a[4 * c + 2] = w00 * v00.z + w01 * v01.z + w10 * v10.z + w11 * v11.z;
    a[4 * c + 3] = w00 * v00.w + w01 * v01.w + w10 * v10.w + w11 * v11.w;
  }
  o0 = fminf(fmaxf(a[0] * r + a[1] * g + a[2] * bl + a[9], 0.0f), 1.0f);
  o1 = fminf(fmaxf(a[3] * r + a[4] * g + a[5] * bl + a[10], 0.0f), 1.0f);
  o2 = fminf(fmaxf(a[6] * r + a[7] * g + a[8] * bl + a[11], 0.0f), 1.0f);
}

// 448 threads = 7 waves; 896 = 2 * 448 so each thread owns exactly 2 pixels
// (no tail divergence). Grid = 4 * 896 rows. LDS: 64 + 768 + 1536 floats
// = 9.25 KB -> occupancy capped by waves (4 blocks = 28 waves/CU).
__global__ __launch_bounds__(448) void k_pixel(
    const float* __restrict__ img, const float* __restrict__ gsem,
    const float* __restrict__ rg, const float* __restrict__ rl,
    float* __restrict__ out) {
  int blk = blockIdx.x;
  int b = blk / 896;
  int h = blk - b * 896;
  int t = threadIdx.x;
  __shared__ float sgr[64];     // y-interp'd gsem row
  __shared__ float sG[768];     // y-interp'd global grid row [x][z][c]
  __shared__ float sL[1536];    // y-interp'd local grid row  [x][z][c]

  // gsem y factors (half-pixel centers, edge clamp)
  float sy = fminf(fmaxf((h + 0.5f) * (1.0f / 14.0f) - 0.5f, 0.0f), 63.0f);
  int y0s = (int)sy;
  int y1s = y0s < 63 ? y0s + 1 : 63;
  float wys = sy - (float)y0s;
  // global slice y factors (linspace 0..S-1 over 896)
  float fyg = (float)h * (7.0f / 895.0f);
  int y0g = (int)fyg;
  if (y0g > 7) y0g = 7;
  int y1g = y0g < 7 ? y0g + 1 : 7;
  float wyg = fyg - (float)y0g;
  // local slice y factors
  float fyl = (float)h * (15.0f / 895.0f);
  int y0l = (int)fyl;
  if (y0l > 15) y0l = 15;
  int y1l = y0l < 15 ? y0l + 1 : 15;
  float wyl = fyl - (float)y0l;

  if (t < 64) {
    const float* gb = gsem + b * 4096;
    sgr[t] = gb[y0s * 64 + t] * (1.0f - wys) + gb[y1s * 64 + t] * wys;
  }
  {
    const float* g0 = rg + b * 6144 + y0g * 768;
    const float* g1 = rg + b * 6144 + y1g * 768;
    for (int i = t; i < 768; i += 448)
      sG[i] = g0[i] * (1.0f - wyg) + g1[i] * wyg;
    const float* l0 = rl + b * 24576 + y0l * 1536;
    const float* l1 = rl + b * 24576 + y1l * 1536;
    for (int i = t; i < 1536; i += 448)
      sL[i] = l0[i] * (1.0f - wyl) + l1[i] * wyl;
  }
  __syncthreads();

#pragma unroll
  for (int ip = 0; ip < 2; ++ip) {
    int w = ip * 448 + t;
    int hw = h * 896 + w;
    float r = img[(b * 3 + 0) * HWPIX + hw];
    float g = img[(b * 3 + 1) * HWPIX + hw];
    float bl = img[(b * 3 + 2) * HWPIX + hw];
    // Lab -> chroma guide (constants folded: (0.5*116 fy - 0.5*16 +
    // 0.25*500|fx-fy| + 0.25*200|fy-fz|)/114)
    float lr = srgb_lin(r), lg = srgb_lin(g), lb2 = srgb_lin(bl);
    float X = 0.412453f * lr + 0.357580f * lg + 0.180423f * lb2;
    float Y = 0.212671f * lr + 0.715160f * lg + 0.072169f * lb2;
    float Z = 0.019334f * lr + 0.119193f * lg + 0.950227f * lb2;
    float fx_ = labf(X * (1.0f / 0.950456f));
    float fy_ = labf(Y);
    float fz_ = labf(Z * (1.0f / 1.088754f));
    float gch = 0.50877193f * fy_ - 0.070175439f +
                1.0964912f * fabsf(fx_ - fy_) + 0.43859649f * fabsf(fy_ - fz_);
    gch = fminf(fmaxf(gch, 0.0f), 1.0f);
    // g_sem bilinear: y already folded into sgr, only x-interp here
    float sx = fminf(fmaxf((w + 0.5f) * (1.0f / 14.0f) - 0.5f, 0.0f), 63.0f);
    int x0s = (int)sx;
    int x1s = x0s < 63 ? x0s + 1 : 63;
    float wxs = sx - (float)x0s;
    float gs = sgr[x0s] * (1.0f - wxs) + sgr[x1s] * wxs;
    float gg = 0.5f * gch + 0.5f * gs;
    __builtin_nontemporal_store(gg, &out[OUT_G + b * HWPIX + hw]);
    // z coordinate shared by both slices (l=8 for both)
    float fzc = fminf(fmaxf(gg * 7.0f, 0.0f), 7.0f);
    int z0 = (int)fzc;
    if (z0 > 7) z0 = 7;
    int z1 = z0 < 7 ? z0 + 1 : 7;
    float wz = fzc - (float)z0;
    float o0, o1, o2;
    slice_lds<8>(sG, w, z0, z1, wz, r, g, bl, o0, o1, o2);
    __builtin_nontemporal_store(o0, &out[(b * 3 + 0) * HWPIX + hw]);
    __builtin_nontemporal_store(o1, &out[(b * 3 + 1) * HWPIX + hw]);
    __builtin_nontemporal_store(o2, &out[(b * 3 + 2) * HWPIX + hw]);
    slice_lds<16>(sL, w, z0, z1, wz, r, g, bl, o0, o1, o2);
    __builtin_nontemporal_store(o0, &out[OUT_IL + (b * 3 + 0) * HWPIX + hw]);
    __builtin_nontemporal_store(o1, &out[OUT_IL + (b * 3 + 1) * HWPIX + hw]);
    __builtin_nontemporal_store(o2, &out[OUT_IL + (b * 3 + 2) * HWPIX + hw]);
  }
}

// ---------------------------------------------------------------------------
extern "C" void kernel_launch(void* const* d_in, const int* in_sizes, int n_in,
                              void* d_out, int out_size, void* d_ws,
                              size_t ws_size, hipStream_t stream) {
  const float* R = (const float*)d_in[0];
  const float* F = (const float*)d_in[1];
  const float* img = (const float*)d_in[2];
  const float* dino_w = (const float*)d_in[5];
  const float* dino_b = (const float*)d_in[6];
  const float* fus_w = (const float*)d_in[7];
  const float* fus_b = (const float*)d_in[8];
  const float* g1_w = (const float*)d_in[9];
  const float* g1_b = (const float*)d_in[10];
  const float* g2_w = (const float*)d_in[11];
  const float* g2_b = (const float*)d_in[12];
  const float* lw = (const float*)d_in[13];
  const float* lb = (const float*)d_in[14];
  const float* gw1 = (const float*)d_in[15];
  const float* gb1 = (const float*)d_in[16];
  const float* gw2 = (const float*)d_in[17];
  const float* gb2 = (const float*)d_in[18];
  float* out = (float*)d_out;
  float* ws = (float*)d_ws;

  float* Wt4 = ws + WS_WT4;
  float* bc = ws + WS_BC;
  float* pooled = ws + WS_POOL;
  float* hbuf = ws + WS_H;
  float* gsem = ws + WS_GSEM;
  float* rg = ws + WS_RG;
  float* rl = ws + WS_RL;
  float* w1T = ws + WS_W1T;

  k_prep<<<642, 256, 0, stream>>>(fus_w, fus_b, dino_w, dino_b, gw1, Wt4, bc, w1T);
  k_guide<<<1024, 256, 0, stream>>>(F, w1T, gb1, gw2, gb2, gsem);
  k_fused_pool<<<256, 1024, 0, stream>>>(R, F, Wt4, bc, pooled);
  k_gap<<<4, 1024, 0, stream>>>(pooled, g1_w, g1_b, hbuf);
  k_gglobal<<<96, 256, 0, stream>>>(hbuf, g2_w, g2_b, out + OUT_GG, rg);
  k_glocal<<<384, 256, 0, stream>>>(pooled, lw, lb, out + OUT_GL, rl);
  k_pixel<<<3584, 448, 0, stream>>>(img, gsem, rg, rl, out);
}

// Round 3
// 318.065 us; speedup vs baseline: 1.3530x; 1.0190x over previous
//
#include <hip/hip_runtime.h>
#include <math.h>

// Problem constants (fixed by setup_inputs): B=4, H=W=896, n_h=n_w=64,
// GS=8, GL=8, LS=16, LL=8, NA=12, ALPHA=0.5
#define HWPIX 802816            // 896*896
#define OUT_IL 9633792          // offset of I_local  (4*3*896*896)
#define OUT_GG 19267584         // offset of G_global
#define OUT_GL 19292160         // offset of G_local
#define OUT_G  19390464         // offset of g

// workspace layout (float offsets)
#define WS_WT4  0               // combined weight, packed [k/4][o][4], 256x640
#define WS_BC   163840          // combined bias, 256
#define WS_POOL 164096          // pooled [b][c][cell], 4*256*256
#define WS_H    426240          // h vector, 4*256
#define WS_GSEM 427264          // g_sem_patch, 4*4096
#define WS_RG   443648          // global grid [b][y][x][z][c], 4*8*8*8*12
#define WS_RL   468224          // local grid  [b][y][x][z][c], 4*16*16*8*12
#define WS_W1T  566528          // guide_w1 packed [k/4][hidden][4], 384*64
#define WS_LWT  591104          // local_w transposed [c][o], 256*96

// Fast transcendentals: v_log_f32 (log2 semantics) / v_exp_f32 (exp2) via
// the clang AMDGPU builtins — the CUDA-style __exp2f/__log2f names collide
// with glibc math.h under hipcc (round-4 compile failure). The libm
// cbrtf/powf expansions were the round-3 VALU hog.
__device__ __forceinline__ float fast_exp2(float x) {
  return __builtin_amdgcn_exp2f(x);
}
__device__ __forceinline__ float fast_log2(float x) {
  return __builtin_amdgcn_logf(x);  // v_log_f32 = log2(x)
}
__device__ __forceinline__ float srgb_lin(float v) {
  // pow path only selected for v > 0.04045 (argument strictly positive)
  float p = fast_exp2(2.4f * fast_log2((v + 0.055f) * (1.0f / 1.055f)));
  return v > 0.04045f ? p : v * (1.0f / 12.92f);
}
__device__ __forceinline__ float labf(float t) {
  // cbrt path only selected for t > 0.008856; log2(0)=-inf -> exp2 -> 0 is
  // discarded by the select, no NaN (t >= 0 always here).
  float c = fast_exp2((1.0f / 3.0f) * fast_log2(t));
  return t > 0.008856f ? c : 7.787f * t + (4.0f / 29.0f);
}

// ---------------------------------------------------------------------------
// K1: combined weight W[o][k] (k<256: fusion Wa; k>=256: Wb @ dino_proj_w)
// packed as Wt4[(k>>2)*256 + o][k&3]; plus bc[o] = fusion_b + Wb @ dino_b.
// block 641 packs guide_w1 -> w1T4; block 642 transposes local_w -> lwT[c][o]
// (coalesced lane access for the fused G_local epilogue in k_fused_pool).
__global__ __launch_bounds__(256) void k_prep(
    const float* __restrict__ fus_w, const float* __restrict__ fus_b,
    const float* __restrict__ dino_w, const float* __restrict__ dino_b,
    const float* __restrict__ gw1, const float* __restrict__ lw,
    float* __restrict__ Wt4, float* __restrict__ bc, float* __restrict__ w1T,
    float* __restrict__ lwT) {
  if (blockIdx.x == 642) {
    int t = threadIdx.x;
    for (int it = 0; it < 96; ++it) {
      int idx = it * 256 + t;       // over 96*256; o = idx>>8, c = idx&255
      int o = idx >> 8;
      int c = idx & 255;
      lwT[c * 96 + o] = lw[o * 256 + c];
    }
    return;
  }
  if (blockIdx.x == 641) {
    int t = threadIdx.x;
    for (int it = 0; it < 96; ++it) {
      int idx = it * 256 + t;       // idx over 384*64; k = idx>>6, h = idx&63
      int h = idx & 63;
      int k = idx >> 6;
      w1T[((k >> 2) * 64 + h) * 4 + (k & 3)] = gw1[h * 384 + k];
    }
    return;
  }
  if (blockIdx.x == 640) {
    int o = threadIdx.x;
    float acc = fus_b[o];
    for (int m = 0; m < 128; ++m) acc += fus_w[o * 384 + 256 + m] * dino_b[m];
    bc[o] = acc;
    return;
  }
  int idx = blockIdx.x * 256 + threadIdx.x;
  int o = idx / 640;
  int k = idx - o * 640;
  float val;
  if (k < 256) {
    val = fus_w[o * 384 + k];
  } else {
    int d = k - 256;
    float acc = 0.0f;
    for (int m = 0; m < 128; ++m)
      acc += fus_w[o * 384 + 256 + m] * dino_w[m * 384 + d];
    val = acc;
  }
  Wt4[((k >> 2) * 256 + o) * 4 + (k & 3)] = val;
}

// ---------------------------------------------------------------------------
// K2: pooled[b][o][cell] = (W @ sum_{16 px} x)/16 + bc.
// Round-1: 1024 threads (16 waves/CU), thread = (cell, o).
// Round-3: FUSED G_local epilogue — a pool block holds all 256 channels of
// its 4 cells in LDS, which is exactly the input G_local needs for those
// cells. Waves 4..9 compute lflat[o][cell] = lb[o] + sum_c lw[o][c] *
// (s[c]/16 + bc[c]) straight from LDS (lwT gives coalesced lane reads) and
// write out4/rl. This removes the separate k_glocal kernel and its ~96 MB
// of pooled L2 re-reads.
__global__ __launch_bounds__(1024) void k_fused_pool(
    const float* __restrict__ R, const float* __restrict__ F,
    const float* __restrict__ Wt4, const float* __restrict__ bc,
    const float* __restrict__ lwT, const float* __restrict__ lb,
    float* __restrict__ pooled, float* __restrict__ out4,
    float* __restrict__ rl) {
  int blk = blockIdx.x;
  int b = blk >> 6;
  int i = (blk >> 2) & 15;
  int jg = blk & 3;
  int t = threadIdx.x;
  int cell = t >> 8;        // 0..3
  int c = t & 255;          // channel / output index
  __shared__ float s[4 * 640];  // [cell][k]
  {  // R part: sum 4x4 pixel block of channel c for this cell
    const float* rb = R + (((b * 256 + c) * 64 + i * 4) * 64) + (jg * 4 + cell) * 4;
    float p = 0.0f;
#pragma unroll
    for (int di = 0; di < 4; ++di) {
      float4 v = *(const float4*)(rb + di * 64);
      p += v.x + v.y + v.z + v.w;
    }
    s[cell * 640 + c] = p;
  }
  {  // F part: thread covers k=256+c (and k=512+c for c<128)
    float a0 = 0.0f, a1 = 0.0f;
    const float* fb = F + (size_t)(b * 4096 + (i * 4) * 64 + (jg * 4 + cell) * 4) * 384;
#pragma unroll
    for (int pix = 0; pix < 16; ++pix) {
      const float* fr = fb + (size_t)((pix >> 2) * 64 + (pix & 3)) * 384;
      a0 += fr[c];
      if (c < 128) a1 += fr[256 + c];
    }
    s[cell * 640 + 256 + c] = a0;
    if (c < 128) s[cell * 640 + 512 + c] = a1;
  }
  __syncthreads();
  float acc = 0.0f;
  const float4* w4 = (const float4*)Wt4;
  const float4* s4 = (const float4*)(s + cell * 640);
#pragma unroll 8
  for (int kk = 0; kk < 160; ++kk) {
    float4 wv = w4[kk * 256 + c];
    float4 sv = s4[kk];
    acc += wv.x * sv.x + wv.y * sv.y + wv.z * sv.z + wv.w * sv.w;
  }
  __syncthreads();
  s[cell * 256 + c] = acc;   // reuse staging LDS for the (cell,o) transpose
  __syncthreads();
  if (t < 256) {
    float bco = bc[t];
    float4 v;
    v.x = s[0 * 256 + t] * (1.0f / 16.0f) + bco;
    v.y = s[1 * 256 + t] * (1.0f / 16.0f) + bco;
    v.z = s[2 * 256 + t] * (1.0f / 16.0f) + bco;
    v.w = s[3 * 256 + t] * (1.0f / 16.0f) + bco;
    *(float4*)(pooled + ((size_t)(b * 256 + t) * 256) + i * 16 + jg * 4) = v;
  } else if (t < 640) {
    // fused G_local: worker (cl, o) over 4 cells x 96 outputs
    int idx = t - 256;
    int cl = idx / 96;            // 0..3
    int o = idx - cl * 96;        // 0..95
    const float* sc_ = s + cl * 256;
    float acc2 = lb[o];
    for (int cc = 0; cc < 256; ++cc) {
      float pv = sc_[cc] * (1.0f / 16.0f) + bc[cc];   // LDS broadcast + L1
      acc2 += lwT[cc * 96 + o] * pv;                  // coalesced lanes
    }
    int cellg = i * 16 + jg * 4 + cl;
    int n = o >> 3, l = o & 7;
    out4[((b * 12 + n) * 256 + cellg) * 8 + l] = acc2;
    rl[b * 24576 + (cellg * 8 + l) * 12 + n] = acc2;
  }
}

// ---------------------------------------------------------------------------
// K3a: f_gap = mean(pooled); h = relu(g1_w @ f_gap + g1_b). One block per b.
// Round-1: 1024 threads, 4-way split over cells (phase 1) and k (phase 2),
// float4 loads — was 4 blocks x 256 scalar-loop threads.
__global__ __launch_bounds__(1024) void k_gap(
    const float* __restrict__ pooled, const float* __restrict__ g1_w,
    const float* __restrict__ g1_b, float* __restrict__ hout) {
  int b = blockIdx.x;
  int t = threadIdx.x;
  int o = t & 255;
  int q = t >> 8;           // 0..3
  __shared__ float f[256];
  __shared__ float part[4][256];
  {  // phase 1: partial sums over 64 cells each
    const float4* pr4 = (const float4*)(pooled + (size_t)(b * 256 + o) * 256 + q * 64);
    float s = 0.0f;
#pragma unroll
    for (int i = 0; i < 16; ++i) {
      float4 v = pr4[i];
      s += v.x + v.y + v.z + v.w;
    }
    part[q][o] = s;
  }
  __syncthreads();
  if (t < 256)
    f[t] = (part[0][t] + part[1][t] + part[2][t] + part[3][t]) * (1.0f / 256.0f);
  __syncthreads();
  {  // phase 2: partial dot over 64 k each
    const float4* wr = (const float4*)(g1_w + o * 256 + q * 64);
    const float4* fq = (const float4*)(f + q * 64);
    float acc = 0.0f;
#pragma unroll
    for (int i = 0; i < 16; ++i) {
      float4 w = wr[i];
      float4 fv = fq[i];
      acc += w.x * fv.x + w.y * fv.y + w.z * fv.z + w.w * fv.w;
    }
    part[q][o] = acc;
  }
  __syncthreads();
  if (t < 256) {
    float a = part[0][t] + part[1][t] + part[2][t] + part[3][t] + g1_b[t];
    hout[b * 256 + t] = fmaxf(a, 0.0f);
  }
}

// ---------------------------------------------------------------------------
// K3b: G_global = h @ g2_w.T + g2_b  (+ slice-layout copy)
// Round-3 rework: was 96 blocks x 256 scalar threads — 256 sequential
// k-iterations of fully uncoalesced g2_w reads (64 lines/wave-instr) on
// 384 waves. Now 1024 threads: thread = (o, k-quarter), 16 float4 loads
// (pipelined 16-deep), LDS partial reduce -> 1536 waves.
__global__ __launch_bounds__(1024) void k_gglobal(
    const float* __restrict__ h, const float* __restrict__ g2_w,
    const float* __restrict__ g2_b, float* __restrict__ out3,
    float* __restrict__ rg) {
  int b = blockIdx.x / 24;
  int og = (blockIdx.x % 24) * 256;
  int t = threadIdx.x;
  int ol = t & 255;
  int q = t >> 8;
  __shared__ float hl[256];
  __shared__ float part[4][256];
  if (t < 256) hl[t] = h[b * 256 + t];
  __syncthreads();
  {
    const float4* wr = (const float4*)(g2_w + (size_t)(og + ol) * 256 + q * 64);
    const float4* hq = (const float4*)(hl + q * 64);
    float acc = 0.0f;
#pragma unroll
    for (int i = 0; i < 16; ++i) {
      float4 w = wr[i];
      float4 hv = hq[i];
      acc += w.x * hv.x + w.y * hv.y + w.z * hv.z + w.w * hv.w;
    }
    part[q][ol] = acc;
  }
  __syncthreads();
  if (t < 256) {
    int o = og + t;
    float a = part[0][t] + part[1][t] + part[2][t] + part[3][t] + g2_b[o];
    out3[b * 6144 + o] = a;
    int n = o >> 9, y = (o >> 6) & 7, x = (o >> 3) & 7, z = o & 7;
    rg[b * 6144 + ((y * 8 + x) * 8 + z) * 12 + n] = a;
  }
}

// ---------------------------------------------------------------------------
// K5: semantic guide. Round-1 rework: was 512 blocks (2 waves/SIMD, 19%
// occupancy) with every F row loaded as a wave-uniform GLOBAL broadcast at
// L3 latency. Now: 1024 blocks of 256 threads; each block stages 16 F rows
// (24 KB) into LDS with coalesced float4 loads; each wave computes 4
// patches (lane = hidden unit) from LDS broadcasts. 4096 waves -> entire
// grid resident, 16 waves/CU.
__global__ __launch_bounds__(256) void k_guide(
    const float* __restrict__ F, const float* __restrict__ w1T,
    const float* __restrict__ b1, const float* __restrict__ w2,
    const float* __restrict__ b2, float* __restrict__ gsem) {
  int t = threadIdx.x;
  int wave = t >> 6;
  int lane = t & 63;
  int pb = blockIdx.x * 16;          // first patch of this block
  __shared__ float4 sF[16 * 96];     // 16 rows x 384 floats
  const float4* Fb = (const float4*)(F + (size_t)pb * 384);
#pragma unroll
  for (int r = 0; r < 6; ++r) sF[r * 256 + t] = Fb[r * 256 + t];
  __syncthreads();
  float accp[4] = {0.0f, 0.0f, 0.0f, 0.0f};
  const float4* w4 = (const float4*)w1T;   // [k/4][64 lanes]
  int prow = wave * 4;               // patch offset within block
  for (int c = 0; c < 48; ++c) {     // 8 k per chunk
    float4 wa = w4[(c * 2 + 0) * 64 + lane];
    float4 wb = w4[(c * 2 + 1) * 64 + lane];
#pragma unroll
    for (int p = 0; p < 4; ++p) {
      float4 va = sF[(prow + p) * 96 + c * 2 + 0];
      float4 vb = sF[(prow + p) * 96 + c * 2 + 1];
      accp[p] += va.x * wa.x + va.y * wa.y + va.z * wa.z + va.w * wa.w +
                 vb.x * wb.x + vb.y * wb.y + vb.z * wb.z + vb.w * wb.w;
    }
  }
  float hb = b1[lane];
  float wl = w2[lane];
  float b2v = b2[0];
  float res = 0.0f;
#pragma unroll
  for (int p = 0; p < 4; ++p) {
    float v = fmaxf(accp[p] + hb, 0.0f) * wl;
#pragma unroll
    for (int m = 32; m >= 1; m >>= 1) v += __shfl_xor(v, m, 64);
    if (lane == p) res = v;   // after butterfly, every lane has the sum
  }
  if (lane < 4) gsem[pb + prow + lane] = 1.0f / (1.0f + expf(-(res + b2v)));
}

// ---------------------------------------------------------------------------
// K6: per-pixel — one block per image ROW (b,h). Within a row, y0/y1/wy are
// constant for the gsem bilinear AND both bilateral slices, so the
// y-interpolation is hoisted: the two needed grid rows are pre-combined
// into LDS once per block. Per pixel the slice then reads only
// 2x * 2z * 12c from LDS (12 ds_read_b128 per slice vs 24 global float4
// gathers before) — this was the ~52% latency-stall in the 100 us version
// (768 B/pixel of per-lane-divergent L1/L2 gather traffic, VALUBusy 48%,
// HBM 14%). LDS bank math: entry stride is 12 floats, so z in 0..7 maps to
// banks {0,12,24,4,16,28,8,20} — all distinct, conflict-free; same-z lanes
// broadcast.
template <int SDIM>
__device__ __forceinline__ void slice_lds(
    const float* __restrict__ sg, int w, int z0, int z1, float wz,
    float r, float g, float bl, float& o0, float& o1, float& o2) {
  constexpr float sc = (float)(SDIM - 1) * (1.0f / 895.0f);
  float fxs = (float)w * sc;
  int x0 = (int)fxs;
  if (x0 > SDIM - 1) x0 = SDIM - 1;
  int x1 = x0 < SDIM - 1 ? x0 + 1 : SDIM - 1;
  float wx = fxs - (float)x0;
  float wz0 = 1.0f - wz;
  float w00 = (1.0f - wx) * wz0;   // (x0, z0)
  float w01 = (1.0f - wx) * wz;    // (x0, z1)
  float w10 = wx * wz0;            // (x1, z0)
  float w11 = wx * wz;             // (x1, z1)
  const float4* p00 = (const float4*)(sg + (x0 * 8 + z0) * 12);
  const float4* p01 = (const float4*)(sg + (x0 * 8 + z1) * 12);
  const float4* p10 = (const float4*)(sg + (x1 * 8 + z0) * 12);
  const float4* p11 = (const float4*)(sg + (x1 * 8 + z1) * 12);
  float a[12];
#pragma unroll
  for (int c = 0; c < 3; ++c) {
    float4 v00 = p00[c], v01 = p01[c], v10 = p10[c], v11 = p11[c];
    a[4 * c + 0] = w00 * v00.x + w01 * v01.x + w10 * v10.x + w11 * v11.x;
    a[4 * c + 1] = w00 * v00.y + w01 * v01.y + w10 * v10.y + w11 * v11.y;
    a[4 * c + 2] = w00 * v00.z + w01 * v01.z + w10 * v10.z + w11 * v11.z;
    a[4 * c + 3] = w00 * v00.w + w01 * v01.w + w10 * v10.w + w11 * v11.w;
  }
  o0 = fminf(fmaxf(a[0] * r + a[1] * g + a[2] * bl + a[9], 0.0f), 1.0f);
  o1 = fminf(fmaxf(a[3] * r + a[4] * g + a[5] * bl + a[10], 0.0f), 1.0f);
  o2 = fminf(fmaxf(a[6] * r + a[7] * g + a[8] * bl + a[11], 0.0f), 1.0f);
}

// 448 threads = 7 waves; 896 = 2 * 448 so each thread owns exactly 2 pixels
// (no tail divergence). Grid = 4 * 896 rows. LDS: 64 + 768 + 1536 floats
// = 9.25 KB -> occupancy capped by waves (4 blocks = 28 waves/CU).
__global__ __launch_bounds__(448) void k_pixel(
    const float* __restrict__ img, const float* __restrict__ gsem,
    const float* __restrict__ rg, const float* __restrict__ rl,
    float* __restrict__ out) {
  int blk = blockIdx.x;
  int b = blk / 896;
  int h = blk - b * 896;
  int t = threadIdx.x;
  __shared__ float sgr[64];     // y-interp'd gsem row
  __shared__ float sG[768];     // y-interp'd global grid row [x][z][c]
  __shared__ float sL[1536];    // y-interp'd local grid row  [x][z][c]

  // gsem y factors (half-pixel centers, edge clamp)
  float sy = fminf(fmaxf((h + 0.5f) * (1.0f / 14.0f) - 0.5f, 0.0f), 63.0f);
  int y0s = (int)sy;
  int y1s = y0s < 63 ? y0s + 1 : 63;
  float wys = sy - (float)y0s;
  // global slice y factors (linspace 0..S-1 over 896)
  float fyg = (float)h * (7.0f / 895.0f);
  int y0g = (int)fyg;
  if (y0g > 7) y0g = 7;
  int y1g = y0g < 7 ? y0g + 1 : 7;
  float wyg = fyg - (float)y0g;
  // local slice y factors
  float fyl = (float)h * (15.0f / 895.0f);
  int y0l = (int)fyl;
  if (y0l > 15) y0l = 15;
  int y1l = y0l < 15 ? y0l + 1 : 15;
  float wyl = fyl - (float)y0l;

  if (t < 64) {
    const float* gb = gsem + b * 4096;
    sgr[t] = gb[y0s * 64 + t] * (1.0f - wys) + gb[y1s * 64 + t] * wys;
  }
  {
    const float* g0 = rg + b * 6144 + y0g * 768;
    const float* g1 = rg + b * 6144 + y1g * 768;
    for (int i = t; i < 768; i += 448)
      sG[i] = g0[i] * (1.0f - wyg) + g1[i] * wyg;
    const float* l0 = rl + b * 24576 + y0l * 1536;
    const float* l1 = rl + b * 24576 + y1l * 1536;
    for (int i = t; i < 1536; i += 448)
      sL[i] = l0[i] * (1.0f - wyl) + l1[i] * wyl;
  }
  __syncthreads();

#pragma unroll
  for (int ip = 0; ip < 2; ++ip) {
    int w = ip * 448 + t;
    int hw = h * 896 + w;
    float r = img[(b * 3 + 0) * HWPIX + hw];
    float g = img[(b * 3 + 1) * HWPIX + hw];
    float bl = img[(b * 3 + 2) * HWPIX + hw];
    // Lab -> chroma guide (constants folded: (0.5*116 fy - 0.5*16 +
    // 0.25*500|fx-fy| + 0.25*200|fy-fz|)/114)
    float lr = srgb_lin(r), lg = srgb_lin(g), lb2 = srgb_lin(bl);
    float X = 0.412453f * lr + 0.357580f * lg + 0.180423f * lb2;
    float Y = 0.212671f * lr + 0.715160f * lg + 0.072169f * lb2;
    float Z = 0.019334f * lr + 0.119193f * lg + 0.950227f * lb2;
    float fx_ = labf(X * (1.0f / 0.950456f));
    float fy_ = labf(Y);
    float fz_ = labf(Z * (1.0f / 1.088754f));
    float gch = 0.50877193f * fy_ - 0.070175439f +
                1.0964912f * fabsf(fx_ - fy_) + 0.43859649f * fabsf(fy_ - fz_);
    gch = fminf(fmaxf(gch, 0.0f), 1.0f);
    // g_sem bilinear: y already folded into sgr, only x-interp here
    float sx = fminf(fmaxf((w + 0.5f) * (1.0f / 14.0f) - 0.5f, 0.0f), 63.0f);
    int x0s = (int)sx;
    int x1s = x0s < 63 ? x0s + 1 : 63;
    float wxs = sx - (float)x0s;
    float gs = sgr[x0s] * (1.0f - wxs) + sgr[x1s] * wxs;
    float gg = 0.5f * gch + 0.5f * gs;
    __builtin_nontemporal_store(gg, &out[OUT_G + b * HWPIX + hw]);
    // z coordinate shared by both slices (l=8 for both)
    float fzc = fminf(fmaxf(gg * 7.0f, 0.0f), 7.0f);
    int z0 = (int)fzc;
    if (z0 > 7) z0 = 7;
    int z1 = z0 < 7 ? z0 + 1 : 7;
    float wz = fzc - (float)z0;
    float o0, o1, o2;
    slice_lds<8>(sG, w, z0, z1, wz, r, g, bl, o0, o1, o2);
    __builtin_nontemporal_store(o0, &out[(b * 3 + 0) * HWPIX + hw]);
    __builtin_nontemporal_store(o1, &out[(b * 3 + 1) * HWPIX + hw]);
    __builtin_nontemporal_store(o2, &out[(b * 3 + 2) * HWPIX + hw]);
    slice_lds<16>(sL, w, z0, z1, wz, r, g, bl, o0, o1, o2);
    __builtin_nontemporal_store(o0, &out[OUT_IL + (b * 3 + 0) * HWPIX + hw]);
    __builtin_nontemporal_store(o1, &out[OUT_IL + (b * 3 + 1) * HWPIX + hw]);
    __builtin_nontemporal_store(o2, &out[OUT_IL + (b * 3 + 2) * HWPIX + hw]);
  }
}

// ---------------------------------------------------------------------------
extern "C" void kernel_launch(void* const* d_in, const int* in_sizes, int n_in,
                              void* d_out, int out_size, void* d_ws,
                              size_t ws_size, hipStream_t stream) {
  const float* R = (const float*)d_in[0];
  const float* F = (const float*)d_in[1];
  const float* img = (const float*)d_in[2];
  const float* dino_w = (const float*)d_in[5];
  const float* dino_b = (const float*)d_in[6];
  const float* fus_w = (const float*)d_in[7];
  const float* fus_b = (const float*)d_in[8];
  const float* g1_w = (const float*)d_in[9];
  const float* g1_b = (const float*)d_in[10];
  const float* g2_w = (const float*)d_in[11];
  const float* g2_b = (const float*)d_in[12];
  const float* lw = (const float*)d_in[13];
  const float* lb = (const float*)d_in[14];
  const float* gw1 = (const float*)d_in[15];
  const float* gb1 = (const float*)d_in[16];
  const float* gw2 = (const float*)d_in[17];
  const float* gb2 = (const float*)d_in[18];
  float* out = (float*)d_out;
  float* ws = (float*)d_ws;

  float* Wt4 = ws + WS_WT4;
  float* bc = ws + WS_BC;
  float* pooled = ws + WS_POOL;
  float* hbuf = ws + WS_H;
  float* gsem = ws + WS_GSEM;
  float* rg = ws + WS_RG;
  float* rl = ws + WS_RL;
  float* w1T = ws + WS_W1T;
  float* lwT = ws + WS_LWT;

  k_prep<<<643, 256, 0, stream>>>(fus_w, fus_b, dino_w, dino_b, gw1, lw,
                                  Wt4, bc, w1T, lwT);
  k_guide<<<1024, 256, 0, stream>>>(F, w1T, gb1, gw2, gb2, gsem);
  k_fused_pool<<<256, 1024, 0, stream>>>(R, F, Wt4, bc, lwT, lb,
                                         pooled, out + OUT_GL, rl);
  k_gap<<<4, 1024, 0, stream>>>(pooled, g1_w, g1_b, hbuf);
  k_gglobal<<<96, 1024, 0, stream>>>(hbuf, g2_w, g2_b, out + OUT_GG, rg);
  k_pixel<<<3584, 448, 0, stream>>>(img, gsem, rg, rl, out);
}

// Round 4
// 306.771 us; speedup vs baseline: 1.4028x; 1.0368x over previous
//
#include <hip/hip_runtime.h>
#include <math.h>

// Problem constants (fixed by setup_inputs): B=4, H=W=896, n_h=n_w=64,
// GS=8, GL=8, LS=16, LL=8, NA=12, ALPHA=0.5
#define HWPIX 802816            // 896*896
#define OUT_IL 9633792          // offset of I_local  (4*3*896*896)
#define OUT_GG 19267584         // offset of G_global
#define OUT_GL 19292160         // offset of G_local
#define OUT_G  19390464         // offset of g

// workspace layout (float offsets)
#define WS_WT4  0               // combined weight, packed [k/4][o][4], 256x640
#define WS_BC   163840          // combined bias, 256
#define WS_POOL 164096          // pooled [b][c][cell], 4*256*256
#define WS_H    426240          // (unused since round 4)
#define WS_GSEM 427264          // g_sem_patch, 4*4096
#define WS_RG   443648          // global grid [b][y][x][z][c], 4*8*8*8*12
#define WS_RL   468224          // local grid  [b][y][x][z][c], 4*16*16*8*12
#define WS_W1T  566528          // guide_w1 packed [kq][k4][hg][hl][4], 384*64
#define WS_LWT  591104          // local_w transposed [c][o], 256*96

__device__ __forceinline__ float fast_exp2(float x) {
  return __builtin_amdgcn_exp2f(x);
}
__device__ __forceinline__ float fast_log2(float x) {
  return __builtin_amdgcn_logf(x);  // v_log_f32 = log2(x)
}
__device__ __forceinline__ float srgb_lin(float v) {
  float p = fast_exp2(2.4f * fast_log2((v + 0.055f) * (1.0f / 1.055f)));
  return v > 0.04045f ? p : v * (1.0f / 12.92f);
}
__device__ __forceinline__ float labf(float t) {
  float c = fast_exp2((1.0f / 3.0f) * fast_log2(t));
  return t > 0.008856f ? c : 7.787f * t + (4.0f / 29.0f);
}

// ---------------------------------------------------------------------------
// K1: combined weight W[o][k] packed Wt4[(k>>2)*256+o][k&3]; bc = fused bias.
// block 641 packs guide_w1 for the k-split guide: w1T[kq][k4][hg][hl][4]
// (k = kq*96+k4*4+j, h = hg*16+hl). block 642 transposes local_w -> lwT.
__global__ __launch_bounds__(256) void k_prep(
    const float* __restrict__ fus_w, const float* __restrict__ fus_b,
    const float* __restrict__ dino_w, const float* __restrict__ dino_b,
    const float* __restrict__ gw1, const float* __restrict__ lw,
    float* __restrict__ Wt4, float* __restrict__ bc, float* __restrict__ w1T,
    float* __restrict__ lwT) {
  if (blockIdx.x == 642) {
    int t = threadIdx.x;
    for (int it = 0; it < 96; ++it) {
      int idx = it * 256 + t;       // over 96*256; o = idx>>8, c = idx&255
      int o = idx >> 8;
      int c = idx & 255;
      lwT[c * 96 + o] = lw[o * 256 + c];
    }
    return;
  }
  if (blockIdx.x == 641) {
    int t = threadIdx.x;
    for (int it = 0; it < 96; ++it) {
      int idx = it * 256 + t;       // idx over 384*64; k = idx>>6, h = idx&63
      int h = idx & 63;
      int k = idx >> 6;
      int kq = k / 96;              // 0..3
      int krem = k - kq * 96;
      int k4 = krem >> 2;           // 0..23
      int j = krem & 3;
      int hg = h >> 4, hl = h & 15;
      w1T[((((kq * 24 + k4) * 4 + hg) * 16) + hl) * 4 + j] = gw1[h * 384 + k];
    }
    return;
  }
  if (blockIdx.x == 640) {
    int o = threadIdx.x;
    float acc = fus_b[o];
    for (int m = 0; m < 128; ++m) acc += fus_w[o * 384 + 256 + m] * dino_b[m];
    bc[o] = acc;
    return;
  }
  int idx = blockIdx.x * 256 + threadIdx.x;
  int o = idx / 640;
  int k = idx - o * 640;
  float val;
  if (k < 256) {
    val = fus_w[o * 384 + k];
  } else {
    int d = k - 256;
    float acc = 0.0f;
    for (int m = 0; m < 128; ++m)
      acc += fus_w[o * 384 + 256 + m] * dino_w[m * 384 + d];
    val = acc;
  }
  Wt4[((k >> 2) * 256 + o) * 4 + (k & 3)] = val;
}

// ---------------------------------------------------------------------------
// K2: pooled + fused G_local epilogue (round-3). Unchanged in round 4.
__global__ __launch_bounds__(1024) void k_fused_pool(
    const float* __restrict__ R, const float* __restrict__ F,
    const float* __restrict__ Wt4, const float* __restrict__ bc,
    const float* __restrict__ lwT, const float* __restrict__ lb,
    float* __restrict__ pooled, float* __restrict__ out4,
    float* __restrict__ rl) {
  int blk = blockIdx.x;
  int b = blk >> 6;
  int i = (blk >> 2) & 15;
  int jg = blk & 3;
  int t = threadIdx.x;
  int cell = t >> 8;        // 0..3
  int c = t & 255;          // channel / output index
  __shared__ float s[4 * 640];  // [cell][k]
  {  // R part
    const float* rb = R + (((b * 256 + c) * 64 + i * 4) * 64) + (jg * 4 + cell) * 4;
    float p = 0.0f;
#pragma unroll
    for (int di = 0; di < 4; ++di) {
      float4 v = *(const float4*)(rb + di * 64);
      p += v.x + v.y + v.z + v.w;
    }
    s[cell * 640 + c] = p;
  }
  {  // F part
    float a0 = 0.0f, a1 = 0.0f;
    const float* fb = F + (size_t)(b * 4096 + (i * 4) * 64 + (jg * 4 + cell) * 4) * 384;
#pragma unroll
    for (int pix = 0; pix < 16; ++pix) {
      const float* fr = fb + (size_t)((pix >> 2) * 64 + (pix & 3)) * 384;
      a0 += fr[c];
      if (c < 128) a1 += fr[256 + c];
    }
    s[cell * 640 + 256 + c] = a0;
    if (c < 128) s[cell * 640 + 512 + c] = a1;
  }
  __syncthreads();
  float acc = 0.0f;
  const float4* w4 = (const float4*)Wt4;
  const float4* s4 = (const float4*)(s + cell * 640);
#pragma unroll 8
  for (int kk = 0; kk < 160; ++kk) {
    float4 wv = w4[kk * 256 + c];
    float4 sv = s4[kk];
    acc += wv.x * sv.x + wv.y * sv.y + wv.z * sv.z + wv.w * sv.w;
  }
  __syncthreads();
  s[cell * 256 + c] = acc;   // reuse staging LDS for the (cell,o) transpose
  __syncthreads();
  if (t < 256) {
    float bco = bc[t];
    float4 v;
    v.x = s[0 * 256 + t] * (1.0f / 16.0f) + bco;
    v.y = s[1 * 256 + t] * (1.0f / 16.0f) + bco;
    v.z = s[2 * 256 + t] * (1.0f / 16.0f) + bco;
    v.w = s[3 * 256 + t] * (1.0f / 16.0f) + bco;
    *(float4*)(pooled + ((size_t)(b * 256 + t) * 256) + i * 16 + jg * 4) = v;
  } else if (t < 640) {
    int idx = t - 256;
    int cl = idx / 96;            // 0..3
    int o = idx - cl * 96;        // 0..95
    const float* sc_ = s + cl * 256;
    float acc2 = lb[o];
    for (int cc = 0; cc < 256; ++cc) {
      float pv = sc_[cc] * (1.0f / 16.0f) + bc[cc];
      acc2 += lwT[cc * 96 + o] * pv;
    }
    int cellg = i * 16 + jg * 4 + cl;
    int n = o >> 3, l = o & 7;
    out4[((b * 12 + n) * 256 + cellg) * 8 + l] = acc2;
    rl[b * 24576 + (cellg * 8 + l) * 12 + n] = acc2;
  }
}

// ---------------------------------------------------------------------------
// K3 (round-4 merge of k_gap + k_gglobal): block = (b, og). Each block
// redundantly recomputes f_gap and h from L2-hot pooled/g1_w (768 KB/block,
// all cached), then its 256-output g2 slice. Removes the 4-block k_gap
// (4 CUs!) and one launch.
__global__ __launch_bounds__(1024) void k_head(
    const float* __restrict__ pooled, const float* __restrict__ g1_w,
    const float* __restrict__ g1_b, const float* __restrict__ g2_w,
    const float* __restrict__ g2_b, float* __restrict__ out3,
    float* __restrict__ rg) {
  int b = blockIdx.x / 24;
  int og = (blockIdx.x % 24) * 256;
  int t = threadIdx.x;
  int ol = t & 255;
  int q = t >> 8;
  __shared__ float part[4][256];
  __shared__ float f[256];
  __shared__ float hv[256];
  {  // f_gap partials
    const float4* pr4 = (const float4*)(pooled + (size_t)(b * 256 + ol) * 256 + q * 64);
    float s = 0.0f;
#pragma unroll
    for (int i = 0; i < 16; ++i) {
      float4 v = pr4[i];
      s += v.x + v.y + v.z + v.w;
    }
    part[q][ol] = s;
  }
  __syncthreads();
  if (t < 256)
    f[t] = (part[0][t] + part[1][t] + part[2][t] + part[3][t]) * (1.0f / 256.0f);
  __syncthreads();
  {  // h = relu(g1_w @ f + g1_b)
    const float4* wr = (const float4*)(g1_w + (size_t)ol * 256 + q * 64);
    const float4* fq = (const float4*)(f + q * 64);
    float acc = 0.0f;
#pragma unroll
    for (int i = 0; i < 16; ++i) {
      float4 w = wr[i];
      float4 v = fq[i];
      acc += w.x * v.x + w.y * v.y + w.z * v.z + w.w * v.w;
    }
    part[q][ol] = acc;
  }
  __syncthreads();
  if (t < 256)
    hv[t] = fmaxf(part[0][t] + part[1][t] + part[2][t] + part[3][t] + g1_b[t], 0.0f);
  __syncthreads();
  {  // g2 slice
    const float4* wr = (const float4*)(g2_w + (size_t)(og + ol) * 256 + q * 64);
    const float4* hq = (const float4*)(hv + q * 64);
    float acc = 0.0f;
#pragma unroll
    for (int i = 0; i < 16; ++i) {
      float4 w = wr[i];
      float4 v = hq[i];
      acc += w.x * v.x + w.y * v.y + w.z * v.z + w.w * v.w;
    }
    part[q][ol] = acc;
  }
  __syncthreads();
  if (t < 256) {
    int o = og + t;
    float a = part[0][t] + part[1][t] + part[2][t] + part[3][t] + g2_b[o];
    out3[b * 6144 + o] = a;
    int n = o >> 9, y = (o >> 6) & 7, x = (o >> 3) & 7, z = o & 7;
    rg[b * 6144 + ((y * 8 + x) * 8 + z) * 12 + n] = a;
  }
}

// ---------------------------------------------------------------------------
// K5: semantic guide, round-4 k-split. Old version: 384 wave-uniform
// broadcast ds_read_b128 per wave (16 B useful each) ~= 74k LDS cyc/CU ~=
// 30 us — LDS-pipe-bound. New: lane = (kq = lane>>4, hl = lane&15); each
// lane accumulates 4 patches x 4 hidden-groups over its k-quarter. One LDS
// instruction now serves 4 distinct vec4 (64 B useful) -> 96 LDS instr/wave.
// sF padded per-kq (25-vec4 stride) so the 4 addresses land on disjoint
// banks. kq folded with 2 shfl_xor; h folded with 4.
__global__ __launch_bounds__(256) void k_guide(
    const float* __restrict__ F, const float* __restrict__ w1T,
    const float* __restrict__ b1, const float* __restrict__ w2,
    const float* __restrict__ b2, float* __restrict__ gsem) {
  int t = threadIdx.x;
  int wave = t >> 6;
  int lane = t & 63;
  int kq = lane >> 4;
  int hl = lane & 15;
  int pb = blockIdx.x * 16;          // first patch of this block
  __shared__ float4 sF[16 * 4 * 25]; // [row][kq][25] (24 used + 1 pad)
  const float4* Fb = (const float4*)(F + (size_t)pb * 384);
#pragma unroll
  for (int r6 = 0; r6 < 6; ++r6) {
    int g = r6 * 256 + t;            // 0..1535 over [16 rows][96 vec4]
    int row = g / 96;
    int col = g - row * 96;
    int cq = col / 24;
    int c4 = col - cq * 24;
    sF[(row * 4 + cq) * 25 + c4] = Fb[g];
  }
  __syncthreads();
  float acc[4][4];                   // [patch][hidden-group]
#pragma unroll
  for (int p = 0; p < 4; ++p)
#pragma unroll
    for (int hg = 0; hg < 4; ++hg) acc[p][hg] = 0.0f;
  const float4* w4 = (const float4*)w1T;
  int prow = wave * 4;
  for (int k4 = 0; k4 < 24; ++k4) {
    float4 wv0 = w4[((kq * 24 + k4) * 4 + 0) * 16 + hl];
    float4 wv1 = w4[((kq * 24 + k4) * 4 + 1) * 16 + hl];
    float4 wv2 = w4[((kq * 24 + k4) * 4 + 2) * 16 + hl];
    float4 wv3 = w4[((kq * 24 + k4) * 4 + 3) * 16 + hl];
#pragma unroll
    for (int p = 0; p < 4; ++p) {
      float4 fv = sF[((prow + p) * 4 + kq) * 25 + k4];
      acc[p][0] += fv.x * wv0.x + fv.y * wv0.y + fv.z * wv0.z + fv.w * wv0.w;
      acc[p][1] += fv.x * wv1.x + fv.y * wv1.y + fv.z * wv1.z + fv.w * wv1.w;
      acc[p][2] += fv.x * wv2.x + fv.y * wv2.y + fv.z * wv2.z + fv.w * wv2.w;
      acc[p][3] += fv.x * wv3.x + fv.y * wv3.y + fv.z * wv3.z + fv.w * wv3.w;
    }
  }
  // fold the kq split (lane bits 4,5)
#pragma unroll
  for (int p = 0; p < 4; ++p)
#pragma unroll
    for (int hg = 0; hg < 4; ++hg) {
      float v = acc[p][hg];
      v += __shfl_xor(v, 16, 64);
      v += __shfl_xor(v, 32, 64);
      acc[p][hg] = v;
    }
  float b1v[4], w2v[4];
#pragma unroll
  for (int hg = 0; hg < 4; ++hg) {
    b1v[hg] = b1[hg * 16 + hl];
    w2v[hg] = w2[hg * 16 + hl];
  }
  float b2v = b2[0];
  float res = 0.0f;
#pragma unroll
  for (int p = 0; p < 4; ++p) {
    float v = 0.0f;
#pragma unroll
    for (int hg = 0; hg < 4; ++hg)
      v += fmaxf(acc[p][hg] + b1v[hg], 0.0f) * w2v[hg];
#pragma unroll
    for (int m = 8; m >= 1; m >>= 1) v += __shfl_xor(v, m, 64);
    if (lane == p) res = v;
  }
  if (lane < 4) gsem[pb + prow + lane] = 1.0f / (1.0f + expf(-(res + b2v)));
}

// ---------------------------------------------------------------------------
// K6: per-pixel, one block per row. Round-4: img loads prefetched and
// staging loads batched (load-all-then-write) so the block-start L2/HBM
// latency overlaps instead of serializing — the LDS slice reads themselves
// (24 ds_read_b128/px = 384 B/px ~= 23.5 us chip floor) are algorithmically
// required and stay. Strided 2-px mapping keeps x wave-uniform (conflict-
// free LDS: z stride 12 -> banks {0,12,24,4,16,28,8,20}).
template <int SDIM>
__device__ __forceinline__ void slice_lds(
    const float* __restrict__ sg, int w, int z0, int z1, float wz,
    float r, float g, float bl, float& o0, float& o1, float& o2) {
  constexpr float sc = (float)(SDIM - 1) * (1.0f / 895.0f);
  float fxs = (float)w * sc;
  int x0 = (int)fxs;
  if (x0 > SDIM - 1) x0 = SDIM - 1;
  int x1 = x0 < SDIM - 1 ? x0 + 1 : SDIM - 1;
  float wx = fxs - (float)x0;
  float wz0 = 1.0f - wz;
  float w00 = (1.0f - wx) * wz0;
  float w01 = (1.0f - wx) * wz;
  float w10 = wx * wz0;
  float w11 = wx * wz;
  const float4* p00 = (const float4*)(sg + (x0 * 8 + z0) * 12);
  const float4* p01 = (const float4*)(sg + (x0 * 8 + z1) * 12);
  const float4* p10 = (const float4*)(sg + (x1 * 8 + z0) * 12);
  const float4* p11 = (const float4*)(sg + (x1 * 8 + z1) * 12);
  float a[12];
#pragma unroll
  for (int c = 0; c < 3; ++c) {
    float4 v00 = p00[c], v01 = p01[c], v10 = p10[c], v11 = p11[c];
    a[4 * c + 0] = w00 * v00.x + w01 * v01.x + w10 * v10.x + w11 * v11.x;
    a[4 * c + 1] = w00 * v00.y + w01 * v01.y + w10 * v10.y + w11 * v11.y;
    a[4 * c + 2] = w00 * v00.z + w01 * v01.z + w10 * v10.z + w11 * v11.z;
    a[4 * c + 3] = w00 * v00.w + w01 * v01.w + w10 * v10.w + w11 * v11.w;
  }
  o0 = fminf(fmaxf(a[0] * r + a[1] * g + a[2] * bl + a[9], 0.0f), 1.0f);
  o1 = fminf(fmaxf(a[3] * r + a[4] * g + a[5] * bl + a[10], 0.0f), 1.0f);
  o2 = fminf(fmaxf(a[6] * r + a[7] * g + a[8] * bl + a[11], 0.0f), 1.0f);
}

__global__ __launch_bounds__(448) void k_pixel(
    const float* __restrict__ img, const float* __restrict__ gsem,
    const float* __restrict__ rg, const float* __restrict__ rl,
    float* __restrict__ out) {
  int blk = blockIdx.x;
  int b = blk / 896;
  int h = blk - b * 896;
  int t = threadIdx.x;
  __shared__ float sgr[64];     // y-interp'd gsem row
  __shared__ float sG[768];     // y-interp'd global grid row [x][z][c]
  __shared__ float sL[1536];    // y-interp'd local grid row  [x][z][c]

  // ---- img prefetch: issue the 6 pixel loads first so HBM latency
  // overlaps the (L2-latency-bound) staging phase.
  int hwA = h * 896 + t;
  int hwB = hwA + 448;
  const float* imb = img + (size_t)b * 3 * HWPIX;
  float rrA = imb[hwA],             rrB = imb[hwB];
  float ggA = imb[HWPIX + hwA],     ggB = imb[HWPIX + hwB];
  float bbA = imb[2 * HWPIX + hwA], bbB = imb[2 * HWPIX + hwB];

  // y factors
  float sy = fminf(fmaxf((h + 0.5f) * (1.0f / 14.0f) - 0.5f, 0.0f), 63.0f);
  int y0s = (int)sy;
  int y1s = y0s < 63 ? y0s + 1 : 63;
  float wys = sy - (float)y0s;
  float fyg = (float)h * (7.0f / 895.0f);
  int y0g = (int)fyg;
  if (y0g > 7) y0g = 7;
  int y1g = y0g < 7 ? y0g + 1 : 7;
  float wyg = fyg - (float)y0g;
  float fyl = (float)h * (15.0f / 895.0f);
  int y0l = (int)fyl;
  if (y0l > 15) y0l = 15;
  int y1l = y0l < 15 ? y0l + 1 : 15;
  float wyl = fyl - (float)y0l;

  // ---- staging: batch all loads, then all LDS writes
  const float* g0 = rg + b * 6144 + y0g * 768;
  const float* g1 = rg + b * 6144 + y1g * 768;
  const float* l0 = rl + b * 24576 + y0l * 1536;
  const float* l1 = rl + b * 24576 + y1l * 1536;
  float ga0 = g0[t], gb0 = g1[t];
  float ga1 = 0.0f, gb1 = 0.0f;
  if (t < 320) { ga1 = g0[t + 448]; gb1 = g1[t + 448]; }
  float la0 = l0[t], lb0 = l1[t];
  float la1 = l0[t + 448], lb1 = l1[t + 448];
  float la2 = l0[t + 896], lb2s = l1[t + 896];
  float la3 = 0.0f, lb3 = 0.0f;
  if (t < 192) { la3 = l0[t + 1344]; lb3 = l1[t + 1344]; }
  float sg0 = 0.0f, sg1 = 0.0f;
  if (t < 64) {
    const float* gbp = gsem + b * 4096;
    sg0 = gbp[y0s * 64 + t];
    sg1 = gbp[y1s * 64 + t];
  }
  sG[t] = ga0 * (1.0f - wyg) + gb0 * wyg;
  if (t < 320) sG[t + 448] = ga1 * (1.0f - wyg) + gb1 * wyg;
  sL[t] = la0 * (1.0f - wyl) + lb0 * wyl;
  sL[t + 448] = la1 * (1.0f - wyl) + lb1 * wyl;
  sL[t + 896] = la2 * (1.0f - wyl) + lb2s * wyl;
  if (t < 192) sL[t + 1344] = la3 * (1.0f - wyl) + lb3 * wyl;
  if (t < 64) sgr[t] = sg0 * (1.0f - wys) + sg1 * wys;
  __syncthreads();

  float rr_[2] = {rrA, rrB}, gg_[2] = {ggA, ggB}, bb_[2] = {bbA, bbB};
#pragma unroll
  for (int ip = 0; ip < 2; ++ip) {
    int w = ip * 448 + t;
    int hw = h * 896 + w;
    float r = rr_[ip];
    float g = gg_[ip];
    float bl = bb_[ip];
    float lr = srgb_lin(r), lg = srgb_lin(g), lb2 = srgb_lin(bl);
    float X = 0.412453f * lr + 0.357580f * lg + 0.180423f * lb2;
    float Y = 0.212671f * lr + 0.715160f * lg + 0.072169f * lb2;
    float Z = 0.019334f * lr + 0.119193f * lg + 0.950227f * lb2;
    float fx_ = labf(X * (1.0f / 0.950456f));
    float fy_ = labf(Y);
    float fz_ = labf(Z * (1.0f / 1.088754f));
    float gch = 0.50877193f * fy_ - 0.070175439f +
                1.0964912f * fabsf(fx_ - fy_) + 0.43859649f * fabsf(fy_ - fz_);
    gch = fminf(fmaxf(gch, 0.0f), 1.0f);
    float sx = fminf(fmaxf((w + 0.5f) * (1.0f / 14.0f) - 0.5f, 0.0f), 63.0f);
    int x0s = (int)sx;
    int x1s = x0s < 63 ? x0s + 1 : 63;
    float wxs = sx - (float)x0s;
    float gs = sgr[x0s] * (1.0f - wxs) + sgr[x1s] * wxs;
    float gg = 0.5f * gch + 0.5f * gs;
    __builtin_nontemporal_store(gg, &out[OUT_G + b * HWPIX + hw]);
    float fzc = fminf(fmaxf(gg * 7.0f, 0.0f), 7.0f);
    int z0 = (int)fzc;
    if (z0 > 7) z0 = 7;
    int z1 = z0 < 7 ? z0 + 1 : 7;
    float wz = fzc - (float)z0;
    float o0, o1, o2;
    slice_lds<8>(sG, w, z0, z1, wz, r, g, bl, o0, o1, o2);
    __builtin_nontemporal_store(o0, &out[(b * 3 + 0) * HWPIX + hw]);
    __builtin_nontemporal_store(o1, &out[(b * 3 + 1) * HWPIX + hw]);
    __builtin_nontemporal_store(o2, &out[(b * 3 + 2) * HWPIX + hw]);
    slice_lds<16>(sL, w, z0, z1, wz, r, g, bl, o0, o1, o2);
    __builtin_nontemporal_store(o0, &out[OUT_IL + (b * 3 + 0) * HWPIX + hw]);
    __builtin_nontemporal_store(o1, &out[OUT_IL + (b * 3 + 1) * HWPIX + hw]);
    __builtin_nontemporal_store(o2, &out[OUT_IL + (b * 3 + 2) * HWPIX + hw]);
  }
}

// ---------------------------------------------------------------------------
extern "C" void kernel_launch(void* const* d_in, const int* in_sizes, int n_in,
                              void* d_out, int out_size, void* d_ws,
                              size_t ws_size, hipStream_t stream) {
  const float* R = (const float*)d_in[0];
  const float* F = (const float*)d_in[1];
  const float* img = (const float*)d_in[2];
  const float* dino_w = (const float*)d_in[5];
  const float* dino_b = (const float*)d_in[6];
  const float* fus_w = (const float*)d_in[7];
  const float* fus_b = (const float*)d_in[8];
  const float* g1_w = (const float*)d_in[9];
  const float* g1_b = (const float*)d_in[10];
  const float* g2_w = (const float*)d_in[11];
  const float* g2_b = (const float*)d_in[12];
  const float* lw = (const float*)d_in[13];
  const float* lb = (const float*)d_in[14];
  const float* gw1 = (const float*)d_in[15];
  const float* gb1 = (const float*)d_in[16];
  const float* gw2 = (const float*)d_in[17];
  const float* gb2 = (const float*)d_in[18];
  float* out = (float*)d_out;
  float* ws = (float*)d_ws;

  float* Wt4 = ws + WS_WT4;
  float* bc = ws + WS_BC;
  float* pooled = ws + WS_POOL;
  float* gsem = ws + WS_GSEM;
  float* rg = ws + WS_RG;
  float* rl = ws + WS_RL;
  float* w1T = ws + WS_W1T;
  float* lwT = ws + WS_LWT;

  k_prep<<<643, 256, 0, stream>>>(fus_w, fus_b, dino_w, dino_b, gw1, lw,
                                  Wt4, bc, w1T, lwT);
  k_guide<<<1024, 256, 0, stream>>>(F, w1T, gb1, gw2, gb2, gsem);
  k_fused_pool<<<256, 1024, 0, stream>>>(R, F, Wt4, bc, lwT, lb,
                                         pooled, out + OUT_GL, rl);
  k_head<<<96, 1024, 0, stream>>>(pooled, g1_w, g1_b, g2_w, g2_b,
                                  out + OUT_GG, rg);
  k_pixel<<<3584, 448, 0, stream>>>(img, gsem, rg, rl, out);
}

// Round 5
// 306.415 us; speedup vs baseline: 1.4044x; 1.0012x over previous
//
#include <hip/hip_runtime.h>
#include <math.h>

// Problem constants (fixed by setup_inputs): B=4, H=W=896, n_h=n_w=64,
// GS=8, GL=8, LS=16, LL=8, NA=12, ALPHA=0.5
#define HWPIX 802816            // 896*896
#define OUT_IL 9633792          // offset of I_local  (4*3*896*896)
#define OUT_GG 19267584         // offset of G_global
#define OUT_GL 19292160         // offset of G_local
#define OUT_G  19390464         // offset of g

// workspace layout (float offsets)
#define WS_WT4  0               // combined weight, packed [k/4][o][4], 256x640
#define WS_BC   163840          // combined bias, 256
#define WS_POOL 164096          // pooled [b][c][cell], 4*256*256
#define WS_GSEM 427264          // g_sem_patch, 4*4096
#define WS_RG   443648          // global grid [b][y][x][z][c], 4*8*8*8*12
#define WS_RL   468224          // local grid  [b][y][x][z][c], 4*16*16*8*12
#define WS_W1T  566528          // guide_w1 packed [kq][k4][hg][hl][4], 384*64
#define WS_LWT  591104          // local_w transposed [c][o], 256*96

__device__ __forceinline__ float fast_exp2(float x) {
  return __builtin_amdgcn_exp2f(x);
}
__device__ __forceinline__ float fast_log2(float x) {
  return __builtin_amdgcn_logf(x);  // v_log_f32 = log2(x)
}
__device__ __forceinline__ float srgb_lin(float v) {
  float p = fast_exp2(2.4f * fast_log2((v + 0.055f) * (1.0f / 1.055f)));
  return v > 0.04045f ? p : v * (1.0f / 12.92f);
}
__device__ __forceinline__ float labf(float t) {
  float c = fast_exp2((1.0f / 3.0f) * fast_log2(t));
  return t > 0.008856f ? c : 7.787f * t + (4.0f / 29.0f);
}

// ---------------------------------------------------------------------------
// K1: combined weight W[o][k] packed Wt4[(k>>2)*256+o][k&3]; bc = fused bias.
// block 641 packs guide_w1: w1T[kq][k4][hg][hl][4] (k = kq*96+k4*4+j,
// h = hg*16+hl). block 642 transposes local_w -> lwT.
__global__ __launch_bounds__(256) void k_prep(
    const float* __restrict__ fus_w, const float* __restrict__ fus_b,
    const float* __restrict__ dino_w, const float* __restrict__ dino_b,
    const float* __restrict__ gw1, const float* __restrict__ lw,
    float* __restrict__ Wt4, float* __restrict__ bc, float* __restrict__ w1T,
    float* __restrict__ lwT) {
  if (blockIdx.x == 642) {
    int t = threadIdx.x;
    for (int it = 0; it < 96; ++it) {
      int idx = it * 256 + t;       // over 96*256; o = idx>>8, c = idx&255
      int o = idx >> 8;
      int c = idx & 255;
      lwT[c * 96 + o] = lw[o * 256 + c];
    }
    return;
  }
  if (blockIdx.x == 641) {
    int t = threadIdx.x;
    for (int it = 0; it < 96; ++it) {
      int idx = it * 256 + t;       // idx over 384*64; k = idx>>6, h = idx&63
      int h = idx & 63;
      int k = idx >> 6;
      int kq = k / 96;              // 0..3
      int krem = k - kq * 96;
      int k4 = krem >> 2;           // 0..23
      int j = krem & 3;
      int hg = h >> 4, hl = h & 15;
      w1T[((((kq * 24 + k4) * 4 + hg) * 16) + hl) * 4 + j] = gw1[h * 384 + k];
    }
    return;
  }
  if (blockIdx.x == 640) {
    int o = threadIdx.x;
    float acc = fus_b[o];
    for (int m = 0; m < 128; ++m) acc += fus_w[o * 384 + 256 + m] * dino_b[m];
    bc[o] = acc;
    return;
  }
  int idx = blockIdx.x * 256 + threadIdx.x;
  int o = idx / 640;
  int k = idx - o * 640;
  float val;
  if (k < 256) {
    val = fus_w[o * 384 + k];
  } else {
    int d = k - 256;
    float acc = 0.0f;
    for (int m = 0; m < 128; ++m)
      acc += fus_w[o * 384 + 256 + m] * dino_w[m * 384 + d];
    val = acc;
  }
  Wt4[((k >> 2) * 256 + o) * 4 + (k & 3)] = val;
}

// ---------------------------------------------------------------------------
// K2: pooled + fused G_local epilogue.
// Round-5: 256x1024 -> 512x512 (cell-pair split). The old grid was exactly
// 1 block/CU, so the barrier-separated latency-exposed staging phase could
// never overlap the DS-pipe-bound kk-loop (16 waves x 160 ds_read_b128 x
// ~12cyc ~= 12.8 us/CU). 2 blocks/CU lets one block's staging hide under
// the other's compute. Cost: Wt4 L2 traffic 160->320 MB (~+5 us L2 time,
// amortized across the chip).
__global__ __launch_bounds__(512) void k_fused_pool(
    const float* __restrict__ R, const float* __restrict__ F,
    const float* __restrict__ Wt4, const float* __restrict__ bc,
    const float* __restrict__ lwT, const float* __restrict__ lb,
    float* __restrict__ pooled, float* __restrict__ out4,
    float* __restrict__ rl) {
  int blk = blockIdx.x;
  int b = blk >> 7;
  int i = (blk >> 3) & 15;
  int jg = (blk >> 1) & 3;
  int cp = blk & 1;         // cell-pair
  int t = threadIdx.x;
  int ch = t >> 8;          // 0..1 within pair
  int c = t & 255;          // channel / output index
  int cell = cp * 2 + ch;   // 0..3 within jg group
  __shared__ float s[2 * 640];  // [ch][k]
  {  // R part: sum 4x4 pixel block of channel c for this cell
    const float* rb = R + (((b * 256 + c) * 64 + i * 4) * 64) + (jg * 4 + cell) * 4;
    float p = 0.0f;
#pragma unroll
    for (int di = 0; di < 4; ++di) {
      float4 v = *(const float4*)(rb + di * 64);
      p += v.x + v.y + v.z + v.w;
    }
    s[ch * 640 + c] = p;
  }
  {  // F part: thread covers k=256+c (and k=512+c for c<128)
    float a0 = 0.0f, a1 = 0.0f;
    const float* fb = F + (size_t)(b * 4096 + (i * 4) * 64 + (jg * 4 + cell) * 4) * 384;
#pragma unroll
    for (int pix = 0; pix < 16; ++pix) {
      const float* fr = fb + (size_t)((pix >> 2) * 64 + (pix & 3)) * 384;
      a0 += fr[c];
      if (c < 128) a1 += fr[256 + c];
    }
    s[ch * 640 + 256 + c] = a0;
    if (c < 128) s[ch * 640 + 512 + c] = a1;
  }
  __syncthreads();
  float acc = 0.0f;
  const float4* w4 = (const float4*)Wt4;
  const float4* s4 = (const float4*)(s + ch * 640);
#pragma unroll 8
  for (int kk = 0; kk < 160; ++kk) {
    float4 wv = w4[kk * 256 + c];
    float4 sv = s4[kk];
    acc += wv.x * sv.x + wv.y * sv.y + wv.z * sv.z + wv.w * sv.w;
  }
  __syncthreads();
  s[ch * 256 + c] = acc;   // reuse staging LDS for the (ch,o) transpose
  __syncthreads();
  if (t < 256) {
    float bco = bc[t];
    float2 v;
    v.x = s[0 * 256 + t] * (1.0f / 16.0f) + bco;
    v.y = s[1 * 256 + t] * (1.0f / 16.0f) + bco;
    *(float2*)(pooled + ((size_t)(b * 256 + t) * 256) + i * 16 + jg * 4 + cp * 2) = v;
  } else if (t < 448) {
    // fused G_local: worker (cl2, o) over 2 cells x 96 outputs
    int idx = t - 256;
    int cl2 = idx / 96;           // 0..1
    int o = idx - cl2 * 96;       // 0..95
    const float* sc_ = s + cl2 * 256;
    float acc2 = lb[o];
    for (int cc = 0; cc < 256; ++cc) {
      float pv = sc_[cc] * (1.0f / 16.0f) + bc[cc];   // LDS broadcast + L1
      acc2 += lwT[cc * 96 + o] * pv;                  // coalesced lanes
    }
    int cellg = i * 16 + jg * 4 + cp * 2 + cl2;
    int n = o >> 3, l = o & 7;
    out4[((b * 12 + n) * 256 + cellg) * 8 + l] = acc2;
    rl[b * 24576 + (cellg * 8 + l) * 12 + n] = acc2;
  }
}

// ---------------------------------------------------------------------------
// K3 (merged k_gap + k_gglobal): block = (b, og). Each block redundantly
// recomputes f_gap and h from L2-hot pooled/g1_w, then its 256-output g2
// slice.
__global__ __launch_bounds__(1024) void k_head(
    const float* __restrict__ pooled, const float* __restrict__ g1_w,
    const float* __restrict__ g1_b, const float* __restrict__ g2_w,
    const float* __restrict__ g2_b, float* __restrict__ out3,
    float* __restrict__ rg) {
  int b = blockIdx.x / 24;
  int og = (blockIdx.x % 24) * 256;
  int t = threadIdx.x;
  int ol = t & 255;
  int q = t >> 8;
  __shared__ float part[4][256];
  __shared__ float f[256];
  __shared__ float hv[256];
  {  // f_gap partials
    const float4* pr4 = (const float4*)(pooled + (size_t)(b * 256 + ol) * 256 + q * 64);
    float s = 0.0f;
#pragma unroll
    for (int i = 0; i < 16; ++i) {
      float4 v = pr4[i];
      s += v.x + v.y + v.z + v.w;
    }
    part[q][ol] = s;
  }
  __syncthreads();
  if (t < 256)
    f[t] = (part[0][t] + part[1][t] + part[2][t] + part[3][t]) * (1.0f / 256.0f);
  __syncthreads();
  {  // h = relu(g1_w @ f + g1_b)
    const float4* wr = (const float4*)(g1_w + (size_t)ol * 256 + q * 64);
    const float4* fq = (const float4*)(f + q * 64);
    float acc = 0.0f;
#pragma unroll
    for (int i = 0; i < 16; ++i) {
      float4 w = wr[i];
      float4 v = fq[i];
      acc += w.x * v.x + w.y * v.y + w.z * v.z + w.w * v.w;
    }
    part[q][ol] = acc;
  }
  __syncthreads();
  if (t < 256)
    hv[t] = fmaxf(part[0][t] + part[1][t] + part[2][t] + part[3][t] + g1_b[t], 0.0f);
  __syncthreads();
  {  // g2 slice
    const float4* wr = (const float4*)(g2_w + (size_t)(og + ol) * 256 + q * 64);
    const float4* hq = (const float4*)(hv + q * 64);
    float acc = 0.0f;
#pragma unroll
    for (int i = 0; i < 16; ++i) {
      float4 w = wr[i];
      float4 v = hq[i];
      acc += w.x * v.x + w.y * v.y + w.z * v.z + w.w * v.w;
    }
    part[q][ol] = acc;
  }
  __syncthreads();
  if (t < 256) {
    int o = og + t;
    float a = part[0][t] + part[1][t] + part[2][t] + part[3][t] + g2_b[o];
    out3[b * 6144 + o] = a;
    int n = o >> 9, y = (o >> 6) & 7, x = (o >> 3) & 7, z = o & 7;
    rg[b * 6144 + ((y * 8 + x) * 8 + z) * 12 + n] = a;
  }
}

// ---------------------------------------------------------------------------
// K5: semantic guide, k-split (lane = (kq, hl)). Round-5: 8 patches/wave
// (was 4) — each wave reads the full 96 KB w1T once, so w-traffic scales
// with wave count: 4096 waves x 96 KB = 400 MB L2 (~12 us) -> 2048 waves =
// 200 MB. 512 blocks x 256 thr, 32 patches staged (51 KB LDS, 3 blocks/CU
// = 12 waves/CU). acc[8][4] = 32 VGPR.
__global__ __launch_bounds__(256) void k_guide(
    const float* __restrict__ F, const float* __restrict__ w1T,
    const float* __restrict__ b1, const float* __restrict__ w2,
    const float* __restrict__ b2, float* __restrict__ gsem) {
  int t = threadIdx.x;
  int wave = t >> 6;
  int lane = t & 63;
  int kq = lane >> 4;
  int hl = lane & 15;
  int pb = blockIdx.x * 32;          // first patch of this block
  __shared__ float4 sF[32 * 4 * 25]; // [row][kq][25] (24 used + 1 pad)
  const float4* Fb = (const float4*)(F + (size_t)pb * 384);
#pragma unroll
  for (int r6 = 0; r6 < 12; ++r6) {
    int g = r6 * 256 + t;            // 0..3071 over [32 rows][96 vec4]
    int row = g / 96;
    int col = g - row * 96;
    int cq = col / 24;
    int c4 = col - cq * 24;
    sF[(row * 4 + cq) * 25 + c4] = Fb[g];
  }
  __syncthreads();
  float acc[8][4];                   // [patch][hidden-group]
#pragma unroll
  for (int p = 0; p < 8; ++p)
#pragma unroll
    for (int hg = 0; hg < 4; ++hg) acc[p][hg] = 0.0f;
  const float4* w4 = (const float4*)w1T;
  int prow = wave * 8;
  for (int k4 = 0; k4 < 24; ++k4) {
    float4 wv0 = w4[((kq * 24 + k4) * 4 + 0) * 16 + hl];
    float4 wv1 = w4[((kq * 24 + k4) * 4 + 1) * 16 + hl];
    float4 wv2 = w4[((kq * 24 + k4) * 4 + 2) * 16 + hl];
    float4 wv3 = w4[((kq * 24 + k4) * 4 + 3) * 16 + hl];
#pragma unroll
    for (int p = 0; p < 8; ++p) {
      float4 fv = sF[((prow + p) * 4 + kq) * 25 + k4];
      acc[p][0] += fv.x * wv0.x + fv.y * wv0.y + fv.z * wv0.z + fv.w * wv0.w;
      acc[p][1] += fv.x * wv1.x + fv.y * wv1.y + fv.z * wv1.z + fv.w * wv1.w;
      acc[p][2] += fv.x * wv2.x + fv.y * wv2.y + fv.z * wv2.z + fv.w * wv2.w;
      acc[p][3] += fv.x * wv3.x + fv.y * wv3.y + fv.z * wv3.z + fv.w * wv3.w;
    }
  }
  // fold the kq split (lane bits 4,5)
#pragma unroll
  for (int p = 0; p < 8; ++p)
#pragma unroll
    for (int hg = 0; hg < 4; ++hg) {
      float v = acc[p][hg];
      v += __shfl_xor(v, 16, 64);
      v += __shfl_xor(v, 32, 64);
      acc[p][hg] = v;
    }
  float b1v[4], w2v[4];
#pragma unroll
  for (int hg = 0; hg < 4; ++hg) {
    b1v[hg] = b1[hg * 16 + hl];
    w2v[hg] = w2[hg * 16 + hl];
  }
  float b2v = b2[0];
  float res = 0.0f;
#pragma unroll
  for (int p = 0; p < 8; ++p) {
    float v = 0.0f;
#pragma unroll
    for (int hg = 0; hg < 4; ++hg)
      v += fmaxf(acc[p][hg] + b1v[hg], 0.0f) * w2v[hg];
#pragma unroll
    for (int m = 8; m >= 1; m >>= 1) v += __shfl_xor(v, m, 64);
    if (lane == p) res = v;
  }
  if (lane < 8) gsem[pb + prow + lane] = 1.0f / (1.0f + expf(-(res + b2v)));
}

// ---------------------------------------------------------------------------
// K6: per-pixel, one block per row; y-interp hoisted to LDS; img prefetch +
// batched staging (round-4). DS-pipe floor ~23.5 us (24 ds_read_b128/px is
// algorithmic). Unchanged in round 5.
template <int SDIM>
__device__ __forceinline__ void slice_lds(
    const float* __restrict__ sg, int w, int z0, int z1, float wz,
    float r, float g, float bl, float& o0, float& o1, float& o2) {
  constexpr float sc = (float)(SDIM - 1) * (1.0f / 895.0f);
  float fxs = (float)w * sc;
  int x0 = (int)fxs;
  if (x0 > SDIM - 1) x0 = SDIM - 1;
  int x1 = x0 < SDIM - 1 ? x0 + 1 : SDIM - 1;
  float wx = fxs - (float)x0;
  float wz0 = 1.0f - wz;
  float w00 = (1.0f - wx) * wz0;
  float w01 = (1.0f - wx) * wz;
  float w10 = wx * wz0;
  float w11 = wx * wz;
  const float4* p00 = (const float4*)(sg + (x0 * 8 + z0) * 12);
  const float4* p01 = (const float4*)(sg + (x0 * 8 + z1) * 12);
  const float4* p10 = (const float4*)(sg + (x1 * 8 + z0) * 12);
  const float4* p11 = (const float4*)(sg + (x1 * 8 + z1) * 12);
  float a[12];
#pragma unroll
  for (int c = 0; c < 3; ++c) {
    float4 v00 = p00[c], v01 = p01[c], v10 = p10[c], v11 = p11[c];
    a[4 * c + 0] = w00 * v00.x + w01 * v01.x + w10 * v10.x + w11 * v11.x;
    a[4 * c + 1] = w00 * v00.y + w01 * v01.y + w10 * v10.y + w11 * v11.y;
    a[4 * c + 2] = w00 * v00.z + w01 * v01.z + w10 * v10.z + w11 * v11.z;
    a[4 * c + 3] = w00 * v00.w + w01 * v01.w + w10 * v10.w + w11 * v11.w;
  }
  o0 = fminf(fmaxf(a[0] * r + a[1] * g + a[2] * bl + a[9], 0.0f), 1.0f);
  o1 = fminf(fmaxf(a[3] * r + a[4] * g + a[5] * bl + a[10], 0.0f), 1.0f);
  o2 = fminf(fmaxf(a[6] * r + a[7] * g + a[8] * bl + a[11], 0.0f), 1.0f);
}

__global__ __launch_bounds__(448) void k_pixel(
    const float* __restrict__ img, const float* __restrict__ gsem,
    const float* __restrict__ rg, const float* __restrict__ rl,
    float* __restrict__ out) {
  int blk = blockIdx.x;
  int b = blk / 896;
  int h = blk - b * 896;
  int t = threadIdx.x;
  __shared__ float sgr[64];     // y-interp'd gsem row
  __shared__ float sG[768];     // y-interp'd global grid row [x][z][c]
  __shared__ float sL[1536];    // y-interp'd local grid row  [x][z][c]

  // ---- img prefetch: issue the 6 pixel loads first so HBM latency
  // overlaps the staging phase.
  int hwA = h * 896 + t;
  int hwB = hwA + 448;
  const float* imb = img + (size_t)b * 3 * HWPIX;
  float rrA = imb[hwA],             rrB = imb[hwB];
  float ggA = imb[HWPIX + hwA],     ggB = imb[HWPIX + hwB];
  float bbA = imb[2 * HWPIX + hwA], bbB = imb[2 * HWPIX + hwB];

  // y factors
  float sy = fminf(fmaxf((h + 0.5f) * (1.0f / 14.0f) - 0.5f, 0.0f), 63.0f);
  int y0s = (int)sy;
  int y1s = y0s < 63 ? y0s + 1 : 63;
  float wys = sy - (float)y0s;
  float fyg = (float)h * (7.0f / 895.0f);
  int y0g = (int)fyg;
  if (y0g > 7) y0g = 7;
  int y1g = y0g < 7 ? y0g + 1 : 7;
  float wyg = fyg - (float)y0g;
  float fyl = (float)h * (15.0f / 895.0f);
  int y0l = (int)fyl;
  if (y0l > 15) y0l = 15;
  int y1l = y0l < 15 ? y0l + 1 : 15;
  float wyl = fyl - (float)y0l;

  // ---- staging: batch all loads, then all LDS writes
  const float* g0 = rg + b * 6144 + y0g * 768;
  const float* g1 = rg + b * 6144 + y1g * 768;
  const float* l0 = rl + b * 24576 + y0l * 1536;
  const float* l1 = rl + b * 24576 + y1l * 1536;
  float ga0 = g0[t], gb0 = g1[t];
  float ga1 = 0.0f, gb1 = 0.0f;
  if (t < 320) { ga1 = g0[t + 448]; gb1 = g1[t + 448]; }
  float la0 = l0[t], lb0 = l1[t];
  float la1 = l0[t + 448], lb1 = l1[t + 448];
  float la2 = l0[t + 896], lb2s = l1[t + 896];
  float la3 = 0.0f, lb3 = 0.0f;
  if (t < 192) { la3 = l0[t + 1344]; lb3 = l1[t + 1344]; }
  float sg0 = 0.0f, sg1 = 0.0f;
  if (t < 64) {
    const float* gbp = gsem + b * 4096;
    sg0 = gbp[y0s * 64 + t];
    sg1 = gbp[y1s * 64 + t];
  }
  sG[t] = ga0 * (1.0f - wyg) + gb0 * wyg;
  if (t < 320) sG[t + 448] = ga1 * (1.0f - wyg) + gb1 * wyg;
  sL[t] = la0 * (1.0f - wyl) + lb0 * wyl;
  sL[t + 448] = la1 * (1.0f - wyl) + lb1 * wyl;
  sL[t + 896] = la2 * (1.0f - wyl) + lb2s * wyl;
  if (t < 192) sL[t + 1344] = la3 * (1.0f - wyl) + lb3 * wyl;
  if (t < 64) sgr[t] = sg0 * (1.0f - wys) + sg1 * wys;
  __syncthreads();

  float rr_[2] = {rrA, rrB}, gg_[2] = {ggA, ggB}, bb_[2] = {bbA, bbB};
#pragma unroll
  for (int ip = 0; ip < 2; ++ip) {
    int w = ip * 448 + t;
    int hw = h * 896 + w;
    float r = rr_[ip];
    float g = gg_[ip];
    float bl = bb_[ip];
    float lr = srgb_lin(r), lg = srgb_lin(g), lb2 = srgb_lin(bl);
    float X = 0.412453f * lr + 0.357580f * lg + 0.180423f * lb2;
    float Y = 0.212671f * lr + 0.715160f * lg + 0.072169f * lb2;
    float Z = 0.019334f * lr + 0.119193f * lg + 0.950227f * lb2;
    float fx_ = labf(X * (1.0f / 0.950456f));
    float fy_ = labf(Y);
    float fz_ = labf(Z * (1.0f / 1.088754f));
    float gch = 0.50877193f * fy_ - 0.070175439f +
                1.0964912f * fabsf(fx_ - fy_) + 0.43859649f * fabsf(fy_ - fz_);
    gch = fminf(fmaxf(gch, 0.0f), 1.0f);
    float sx = fminf(fmaxf((w + 0.5f) * (1.0f / 14.0f) - 0.5f, 0.0f), 63.0f);
    int x0s = (int)sx;
    int x1s = x0s < 63 ? x0s + 1 : 63;
    float wxs = sx - (float)x0s;
    float gs = sgr[x0s] * (1.0f - wxs) + sgr[x1s] * wxs;
    float gg = 0.5f * gch + 0.5f * gs;
    __builtin_nontemporal_store(gg, &out[OUT_G + b * HWPIX + hw]);
    float fzc = fminf(fmaxf(gg * 7.0f, 0.0f), 7.0f);
    int z0 = (int)fzc;
    if (z0 > 7) z0 = 7;
    int z1 = z0 < 7 ? z0 + 1 : 7;
    float wz = fzc - (float)z0;
    float o0, o1, o2;
    slice_lds<8>(sG, w, z0, z1, wz, r, g, bl, o0, o1, o2);
    __builtin_nontemporal_store(o0, &out[(b * 3 + 0) * HWPIX + hw]);
    __builtin_nontemporal_store(o1, &out[(b * 3 + 1) * HWPIX + hw]);
    __builtin_nontemporal_store(o2, &out[(b * 3 + 2) * HWPIX + hw]);
    slice_lds<16>(sL, w, z0, z1, wz, r, g, bl, o0, o1, o2);
    __builtin_nontemporal_store(o0, &out[OUT_IL + (b * 3 + 0) * HWPIX + hw]);
    __builtin_nontemporal_store(o1, &out[OUT_IL + (b * 3 + 1) * HWPIX + hw]);
    __builtin_nontemporal_store(o2, &out[OUT_IL + (b * 3 + 2) * HWPIX + hw]);
  }
}

// ---------------------------------------------------------------------------
extern "C" void kernel_launch(void* const* d_in, const int* in_sizes, int n_in,
                              void* d_out, int out_size, void* d_ws,
                              size_t ws_size, hipStream_t stream) {
  const float* R = (const float*)d_in[0];
  const float* F = (const float*)d_in[1];
  const float* img = (const float*)d_in[2];
  const float* dino_w = (const float*)d_in[5];
  const float* dino_b = (const float*)d_in[6];
  const float* fus_w = (const float*)d_in[7];
  const float* fus_b = (const float*)d_in[8];
  const float* g1_w = (const float*)d_in[9];
  const float* g1_b = (const float*)d_in[10];
  const float* g2_w = (const float*)d_in[11];
  const float* g2_b = (const float*)d_in[12];
  const float* lw = (const float*)d_in[13];
  const float* lb = (const float*)d_in[14];
  const float* gw1 = (const float*)d_in[15];
  const float* gb1 = (const float*)d_in[16];
  const float* gw2 = (const float*)d_in[17];
  const float* gb2 = (const float*)d_in[18];
  float* out = (float*)d_out;
  float* ws = (float*)d_ws;

  float* Wt4 = ws + WS_WT4;
  float* bc = ws + WS_BC;
  float* pooled = ws + WS_POOL;
  float* gsem = ws + WS_GSEM;
  float* rg = ws + WS_RG;
  float* rl = ws + WS_RL;
  float* w1T = ws + WS_W1T;
  float* lwT = ws + WS_LWT;

  k_prep<<<643, 256, 0, stream>>>(fus_w, fus_b, dino_w, dino_b, gw1, lw,
                                  Wt4, bc, w1T, lwT);
  k_guide<<<512, 256, 0, stream>>>(F, w1T, gb1, gw2, gb2, gsem);
  k_fused_pool<<<512, 512, 0, stream>>>(R, F, Wt4, bc, lwT, lb,
                                        pooled, out + OUT_GL, rl);
  k_head<<<96, 1024, 0, stream>>>(pooled, g1_w, g1_b, g2_w, g2_b,
                                  out + OUT_GG, rg);
  k_pixel<<<3584, 448, 0, stream>>>(img, gsem, rg, rl, out);
}

// Round 6
// 300.885 us; speedup vs baseline: 1.4302x; 1.0184x over previous
//
#include <hip/hip_runtime.h>
#include <math.h>

// Problem constants (fixed by setup_inputs): B=4, H=W=896, n_h=n_w=64,
// GS=8, GL=8, LS=16, LL=8, NA=12, ALPHA=0.5
#define HWPIX 802816            // 896*896
#define OUT_IL 9633792          // offset of I_local  (4*3*896*896)
#define OUT_GG 19267584         // offset of G_global
#define OUT_GL 19292160         // offset of G_local
#define OUT_G  19390464         // offset of g

// workspace layout (float offsets)
#define WS_WT4  0               // combined weight, packed [k/4][o][4], 256x640
#define WS_BC   163840          // combined bias, 256
#define WS_POOL 164096          // pooled [b][c][cell], 4*256*256
#define WS_GSEM 427264          // g_sem_patch, 4*4096
#define WS_RG   443648          // global grid [b][y][x][z][c], 4*8*8*8*12
#define WS_RL   468224          // local grid  [b][y][x][z][c], 4*16*16*8*12
#define WS_W1T  566528          // guide_w1 packed [kq][k4][hg][hl][4], 384*64
#define WS_LWT  591104          // local_w transposed [c][o], 256*96

__device__ __forceinline__ float fast_exp2(float x) {
  return __builtin_amdgcn_exp2f(x);
}
__device__ __forceinline__ float fast_log2(float x) {
  return __builtin_amdgcn_logf(x);  // v_log_f32 = log2(x)
}
__device__ __forceinline__ float srgb_lin(float v) {
  float p = fast_exp2(2.4f * fast_log2((v + 0.055f) * (1.0f / 1.055f)));
  return v > 0.04045f ? p : v * (1.0f / 12.92f);
}
__device__ __forceinline__ float labf(float t) {
  float c = fast_exp2((1.0f / 3.0f) * fast_log2(t));
  return t > 0.008856f ? c : 7.787f * t + (4.0f / 29.0f);
}

// ---------------------------------------------------------------------------
// K1: combined weight W[o][k] packed Wt4[(k>>2)*256+o][k&3]; bc = fused bias.
// block 641 packs guide_w1: w1T[kq][k4][hg][hl][4] (k = kq*96+k4*4+j,
// h = hg*16+hl). block 642 transposes local_w -> lwT.
__global__ __launch_bounds__(256) void k_prep(
    const float* __restrict__ fus_w, const float* __restrict__ fus_b,
    const float* __restrict__ dino_w, const float* __restrict__ dino_b,
    const float* __restrict__ gw1, const float* __restrict__ lw,
    float* __restrict__ Wt4, float* __restrict__ bc, float* __restrict__ w1T,
    float* __restrict__ lwT) {
  if (blockIdx.x == 642) {
    int t = threadIdx.x;
    for (int it = 0; it < 96; ++it) {
      int idx = it * 256 + t;       // over 96*256; o = idx>>8, c = idx&255
      int o = idx >> 8;
      int c = idx & 255;
      lwT[c * 96 + o] = lw[o * 256 + c];
    }
    return;
  }
  if (blockIdx.x == 641) {
    int t = threadIdx.x;
    for (int it = 0; it < 96; ++it) {
      int idx = it * 256 + t;       // idx over 384*64; k = idx>>6, h = idx&63
      int h = idx & 63;
      int k = idx >> 6;
      int kq = k / 96;              // 0..3
      int krem = k - kq * 96;
      int k4 = krem >> 2;           // 0..23
      int j = krem & 3;
      int hg = h >> 4, hl = h & 15;
      w1T[((((kq * 24 + k4) * 4 + hg) * 16) + hl) * 4 + j] = gw1[h * 384 + k];
    }
    return;
  }
  if (blockIdx.x == 640) {
    int o = threadIdx.x;
    float acc = fus_b[o];
    for (int m = 0; m < 128; ++m) acc += fus_w[o * 384 + 256 + m] * dino_b[m];
    bc[o] = acc;
    return;
  }
  int idx = blockIdx.x * 256 + threadIdx.x;
  int o = idx / 640;
  int k = idx - o * 640;
  float val;
  if (k < 256) {
    val = fus_w[o * 384 + k];
  } else {
    int d = k - 256;
    float acc = 0.0f;
    for (int m = 0; m < 128; ++m)
      acc += fus_w[o * 384 + 256 + m] * dino_w[m * 384 + d];
    val = acc;
  }
  Wt4[((k >> 2) * 256 + o) * 4 + (k & 3)] = val;
}

// ---------------------------------------------------------------------------
// K_MID (round-6): pool (blocks 0..255) + guide (blocks 256..767) fused in
// one dispatch so the two independent kernels' pipes overlap instead of
// serializing (~53 + ~18 us before). 768 blocks x 51.2 KB LDS = exactly 3
// resident blocks/CU.
//
// Pool rework vs round-5 (which was L2-bound: each 256-thread group read
// the full 640 KB Wt4 for ONE cell -> ~19 us/CU of L2 time): thread =
// (K-half q, output o), 4 cell-accumulators per thread; one Wt4 float4
// feeds 4 FMAs -> Wt4 read once per block for 4 cells (164 MB chip-wide,
// ~4.8 us/CU). K-halves folded via an LDS partial reduce.
__global__ __launch_bounds__(512) void k_mid(
    const float* __restrict__ R, const float* __restrict__ F,
    const float* __restrict__ Wt4, const float* __restrict__ bc,
    const float* __restrict__ lwT, const float* __restrict__ lb,
    float* __restrict__ pooled, float* __restrict__ out4,
    float* __restrict__ rl,
    const float* __restrict__ w1T, const float* __restrict__ b1,
    const float* __restrict__ w2, const float* __restrict__ b2,
    float* __restrict__ gsem) {
  __shared__ float4 sbuf4[3200];   // 51.2 KB, shared by both paths
  float* s = (float*)sbuf4;
  int blk = blockIdx.x;
  int t = threadIdx.x;

  if (blk >= 256) {
    // ---------------- guide path (blocks 256..767) ----------------
    int gb = blk - 256;
    int pb = gb * 32;                // 32 patches staged
    const float4* Fb = (const float4*)(F + (size_t)pb * 384);
#pragma unroll
    for (int r6 = 0; r6 < 6; ++r6) {
      int g = r6 * 512 + t;          // 0..3071 over [32 rows][96 vec4]
      int row = g / 96;
      int col = g - row * 96;
      int cq = col / 24;
      int c4 = col - cq * 24;
      sbuf4[(row * 4 + cq) * 25 + c4] = Fb[g];
    }
    __syncthreads();
    if (t < 256) {
      int wave = t >> 6;
      int lane = t & 63;
      int kq = lane >> 4;
      int hl = lane & 15;
      float acc[8][4];               // [patch][hidden-group]
#pragma unroll
      for (int p = 0; p < 8; ++p)
#pragma unroll
        for (int hg = 0; hg < 4; ++hg) acc[p][hg] = 0.0f;
      const float4* w4 = (const float4*)w1T;
      int prow = wave * 8;
      for (int k4 = 0; k4 < 24; ++k4) {
        float4 wv0 = w4[((kq * 24 + k4) * 4 + 0) * 16 + hl];
        float4 wv1 = w4[((kq * 24 + k4) * 4 + 1) * 16 + hl];
        float4 wv2 = w4[((kq * 24 + k4) * 4 + 2) * 16 + hl];
        float4 wv3 = w4[((kq * 24 + k4) * 4 + 3) * 16 + hl];
#pragma unroll
        for (int p = 0; p < 8; ++p) {
          float4 fv = sbuf4[((prow + p) * 4 + kq) * 25 + k4];
          acc[p][0] += fv.x * wv0.x + fv.y * wv0.y + fv.z * wv0.z + fv.w * wv0.w;
          acc[p][1] += fv.x * wv1.x + fv.y * wv1.y + fv.z * wv1.z + fv.w * wv1.w;
          acc[p][2] += fv.x * wv2.x + fv.y * wv2.y + fv.z * wv2.z + fv.w * wv2.w;
          acc[p][3] += fv.x * wv3.x + fv.y * wv3.y + fv.z * wv3.z + fv.w * wv3.w;
        }
      }
#pragma unroll
      for (int p = 0; p < 8; ++p)
#pragma unroll
        for (int hg = 0; hg < 4; ++hg) {
          float v = acc[p][hg];
          v += __shfl_xor(v, 16, 64);
          v += __shfl_xor(v, 32, 64);
          acc[p][hg] = v;
        }
      float b1v[4], w2v[4];
#pragma unroll
      for (int hg = 0; hg < 4; ++hg) {
        b1v[hg] = b1[hg * 16 + hl];
        w2v[hg] = w2[hg * 16 + hl];
      }
      float b2v = b2[0];
      float res = 0.0f;
#pragma unroll
      for (int p = 0; p < 8; ++p) {
        float v = 0.0f;
#pragma unroll
        for (int hg = 0; hg < 4; ++hg)
          v += fmaxf(acc[p][hg] + b1v[hg], 0.0f) * w2v[hg];
#pragma unroll
        for (int m = 8; m >= 1; m >>= 1) v += __shfl_xor(v, m, 64);
        if (lane == p) res = v;
      }
      if (lane < 8) gsem[pb + prow + lane] = 1.0f / (1.0f + expf(-(res + b2v)));
    }
    return;
  }

  // ---------------- pool path (blocks 0..255, 4 cells/block) ----------------
  int b = blk >> 6;
  int i = (blk >> 2) & 15;
  int jg = blk & 3;
  int c = t & 255;          // channel / output index
  int hp = t >> 8;          // 0..1: staging cell-pair, then K-half
  {  // R part: 2 cells per thread
#pragma unroll
    for (int cl2 = 0; cl2 < 2; ++cl2) {
      int cell = hp * 2 + cl2;
      const float* rb = R + (((b * 256 + c) * 64 + i * 4) * 64) + (jg * 4 + cell) * 4;
      float p = 0.0f;
#pragma unroll
      for (int di = 0; di < 4; ++di) {
        float4 v = *(const float4*)(rb + di * 64);
        p += v.x + v.y + v.z + v.w;
      }
      s[cell * 640 + c] = p;
    }
  }
  {  // F part: 2 cells per thread
#pragma unroll
    for (int cl2 = 0; cl2 < 2; ++cl2) {
      int cell = hp * 2 + cl2;
      float a0 = 0.0f, a1 = 0.0f;
      const float* fb = F + (size_t)(b * 4096 + (i * 4) * 64 + (jg * 4 + cell) * 4) * 384;
#pragma unroll
      for (int pix = 0; pix < 16; ++pix) {
        const float* fr = fb + (size_t)((pix >> 2) * 64 + (pix & 3)) * 384;
        a0 += fr[c];
        if (c < 128) a1 += fr[256 + c];
      }
      s[cell * 640 + 256 + c] = a0;
      if (c < 128) s[cell * 640 + 512 + c] = a1;
    }
  }
  __syncthreads();
  // kk-loop: K-half hp, 4 cell accumulators; Wt4 float4 reused 4x
  float acc0 = 0.0f, acc1 = 0.0f, acc2 = 0.0f, acc3 = 0.0f;
  const float4* w4 = (const float4*)Wt4;
  const float4* s40 = (const float4*)(s + 0 * 640);
  const float4* s41 = (const float4*)(s + 1 * 640);
  const float4* s42 = (const float4*)(s + 2 * 640);
  const float4* s43 = (const float4*)(s + 3 * 640);
  int kk0 = hp * 80;
#pragma unroll 8
  for (int kk = kk0; kk < kk0 + 80; ++kk) {
    float4 wv = w4[kk * 256 + c];
    float4 v0 = s40[kk];
    float4 v1 = s41[kk];
    float4 v2 = s42[kk];
    float4 v3 = s43[kk];
    acc0 += wv.x * v0.x + wv.y * v0.y + wv.z * v0.z + wv.w * v0.w;
    acc1 += wv.x * v1.x + wv.y * v1.y + wv.z * v1.z + wv.w * v1.w;
    acc2 += wv.x * v2.x + wv.y * v2.y + wv.z * v2.z + wv.w * v2.w;
    acc3 += wv.x * v3.x + wv.y * v3.y + wv.z * v3.z + wv.w * v3.w;
  }
  // partials at s+2560 (staging area 0..2559 no longer written)
  float* part = s + 2560;   // [q][cl][256]
  part[(hp * 4 + 0) * 256 + c] = acc0;
  part[(hp * 4 + 1) * 256 + c] = acc1;
  part[(hp * 4 + 2) * 256 + c] = acc2;
  part[(hp * 4 + 3) * 256 + c] = acc3;
  __syncthreads();
  if (t < 256) {
    float bco = bc[t];
    float p0 = (part[(0 * 4 + 0) * 256 + t] + part[(1 * 4 + 0) * 256 + t]) * (1.0f / 16.0f) + bco;
    float p1 = (part[(0 * 4 + 1) * 256 + t] + part[(1 * 4 + 1) * 256 + t]) * (1.0f / 16.0f) + bco;
    float p2 = (part[(0 * 4 + 2) * 256 + t] + part[(1 * 4 + 2) * 256 + t]) * (1.0f / 16.0f) + bco;
    float p3 = (part[(0 * 4 + 3) * 256 + t] + part[(1 * 4 + 3) * 256 + t]) * (1.0f / 16.0f) + bco;
    float4 v = make_float4(p0, p1, p2, p3);
    *(float4*)(pooled + ((size_t)(b * 256 + t) * 256) + i * 16 + jg * 4) = v;
    // stash pooled values for the G_local epilogue (staging area is free)
    s[0 * 256 + t] = p0;
    s[1 * 256 + t] = p1;
    s[2 * 256 + t] = p2;
    s[3 * 256 + t] = p3;
  }
  __syncthreads();
  if (t < 384) {
    // fused G_local: worker (cl, o) over 4 cells x 96 outputs
    int cl = t / 96;              // 0..3
    int o = t - cl * 96;          // 0..95
    const float* sc_ = s + cl * 256;
    float a2 = lb[o];
    for (int cc = 0; cc < 256; ++cc)
      a2 += lwT[cc * 96 + o] * sc_[cc];     // coalesced lanes, LDS broadcast
    int cellg = i * 16 + jg * 4 + cl;
    int n = o >> 3, l = o & 7;
    out4[((b * 12 + n) * 256 + cellg) * 8 + l] = a2;
    rl[b * 24576 + (cellg * 8 + l) * 12 + n] = a2;
  }
}

// ---------------------------------------------------------------------------
// K3 (merged k_gap + k_gglobal): block = (b, og). Each block redundantly
// recomputes f_gap and h from L2-hot pooled/g1_w, then its 256-output g2
// slice.
__global__ __launch_bounds__(1024) void k_head(
    const float* __restrict__ pooled, const float* __restrict__ g1_w,
    const float* __restrict__ g1_b, const float* __restrict__ g2_w,
    const float* __restrict__ g2_b, float* __restrict__ out3,
    float* __restrict__ rg) {
  int b = blockIdx.x / 24;
  int og = (blockIdx.x % 24) * 256;
  int t = threadIdx.x;
  int ol = t & 255;
  int q = t >> 8;
  __shared__ float part[4][256];
  __shared__ float f[256];
  __shared__ float hv[256];
  {  // f_gap partials
    const float4* pr4 = (const float4*)(pooled + (size_t)(b * 256 + ol) * 256 + q * 64);
    float s = 0.0f;
#pragma unroll
    for (int i = 0; i < 16; ++i) {
      float4 v = pr4[i];
      s += v.x + v.y + v.z + v.w;
    }
    part[q][ol] = s;
  }
  __syncthreads();
  if (t < 256)
    f[t] = (part[0][t] + part[1][t] + part[2][t] + part[3][t]) * (1.0f / 256.0f);
  __syncthreads();
  {  // h = relu(g1_w @ f + g1_b)
    const float4* wr = (const float4*)(g1_w + (size_t)ol * 256 + q * 64);
    const float4* fq = (const float4*)(f + q * 64);
    float acc = 0.0f;
#pragma unroll
    for (int i = 0; i < 16; ++i) {
      float4 w = wr[i];
      float4 v = fq[i];
      acc += w.x * v.x + w.y * v.y + w.z * v.z + w.w * v.w;
    }
    part[q][ol] = acc;
  }
  __syncthreads();
  if (t < 256)
    hv[t] = fmaxf(part[0][t] + part[1][t] + part[2][t] + part[3][t] + g1_b[t], 0.0f);
  __syncthreads();
  {  // g2 slice
    const float4* wr = (const float4*)(g2_w + (size_t)(og + ol) * 256 + q * 64);
    const float4* hq = (const float4*)(hv + q * 64);
    float acc = 0.0f;
#pragma unroll
    for (int i = 0; i < 16; ++i) {
      float4 w = wr[i];
      float4 v = hq[i];
      acc += w.x * v.x + w.y * v.y + w.z * v.z + w.w * v.w;
    }
    part[q][ol] = acc;
  }
  __syncthreads();
  if (t < 256) {
    int o = og + t;
    float a = part[0][t] + part[1][t] + part[2][t] + part[3][t] + g2_b[o];
    out3[b * 6144 + o] = a;
    int n = o >> 9, y = (o >> 6) & 7, x = (o >> 3) & 7, z = o & 7;
    rg[b * 6144 + ((y * 8 + x) * 8 + z) * 12 + n] = a;
  }
}

// ---------------------------------------------------------------------------
// K6: per-pixel, one block per row; y-interp hoisted to LDS; img prefetch +
// batched staging. DS-pipe floor ~23.5 us (24 ds_read_b128/px algorithmic).
template <int SDIM>
__device__ __forceinline__ void slice_lds(
    const float* __restrict__ sg, int w, int z0, int z1, float wz,
    float r, float g, float bl, float& o0, float& o1, float& o2) {
  constexpr float sc = (float)(SDIM - 1) * (1.0f / 895.0f);
  float fxs = (float)w * sc;
  int x0 = (int)fxs;
  if (x0 > SDIM - 1) x0 = SDIM - 1;
  int x1 = x0 < SDIM - 1 ? x0 + 1 : SDIM - 1;
  float wx = fxs - (float)x0;
  float wz0 = 1.0f - wz;
  float w00 = (1.0f - wx) * wz0;
  float w01 = (1.0f - wx) * wz;
  float w10 = wx * wz0;
  float w11 = wx * wz;
  const float4* p00 = (const float4*)(sg + (x0 * 8 + z0) * 12);
  const float4* p01 = (const float4*)(sg + (x0 * 8 + z1) * 12);
  const float4* p10 = (const float4*)(sg + (x1 * 8 + z0) * 12);
  const float4* p11 = (const float4*)(sg + (x1 * 8 + z1) * 12);
  float a[12];
#pragma unroll
  for (int c = 0; c < 3; ++c) {
    float4 v00 = p00[c], v01 = p01[c], v10 = p10[c], v11 = p11[c];
    a[4 * c + 0] = w00 * v00.x + w01 * v01.x + w10 * v10.x + w11 * v11.x;
    a[4 * c + 1] = w00 * v00.y + w01 * v01.y + w10 * v10.y + w11 * v11.y;
    a[4 * c + 2] = w00 * v00.z + w01 * v01.z + w10 * v10.z + w11 * v11.z;
    a[4 * c + 3] = w00 * v00.w + w01 * v01.w + w10 * v10.w + w11 * v11.w;
  }
  o0 = fminf(fmaxf(a[0] * r + a[1] * g + a[2] * bl + a[9], 0.0f), 1.0f);
  o1 = fminf(fmaxf(a[3] * r + a[4] * g + a[5] * bl + a[10], 0.0f), 1.0f);
  o2 = fminf(fmaxf(a[6] * r + a[7] * g + a[8] * bl + a[11], 0.0f), 1.0f);
}

__global__ __launch_bounds__(448) void k_pixel(
    const float* __restrict__ img, const float* __restrict__ gsem,
    const float* __restrict__ rg, const float* __restrict__ rl,
    float* __restrict__ out) {
  int blk = blockIdx.x;
  int b = blk / 896;
  int h = blk - b * 896;
  int t = threadIdx.x;
  __shared__ float sgr[64];     // y-interp'd gsem row
  __shared__ float sG[768];     // y-interp'd global grid row [x][z][c]
  __shared__ float sL[1536];    // y-interp'd local grid row  [x][z][c]

  // ---- img prefetch: issue the 6 pixel loads first so HBM latency
  // overlaps the staging phase.
  int hwA = h * 896 + t;
  int hwB = hwA + 448;
  const float* imb = img + (size_t)b * 3 * HWPIX;
  float rrA = imb[hwA],             rrB = imb[hwB];
  float ggA = imb[HWPIX + hwA],     ggB = imb[HWPIX + hwB];
  float bbA = imb[2 * HWPIX + hwA], bbB = imb[2 * HWPIX + hwB];

  // y factors
  float sy = fminf(fmaxf((h + 0.5f) * (1.0f / 14.0f) - 0.5f, 0.0f), 63.0f);
  int y0s = (int)sy;
  int y1s = y0s < 63 ? y0s + 1 : 63;
  float wys = sy - (float)y0s;
  float fyg = (float)h * (7.0f / 895.0f);
  int y0g = (int)fyg;
  if (y0g > 7) y0g = 7;
  int y1g = y0g < 7 ? y0g + 1 : 7;
  float wyg = fyg - (float)y0g;
  float fyl = (float)h * (15.0f / 895.0f);
  int y0l = (int)fyl;
  if (y0l > 15) y0l = 15;
  int y1l = y0l < 15 ? y0l + 1 : 15;
  float wyl = fyl - (float)y0l;

  // ---- staging: batch all loads, then all LDS writes
  const float* g0 = rg + b * 6144 + y0g * 768;
  const float* g1 = rg + b * 6144 + y1g * 768;
  const float* l0 = rl + b * 24576 + y0l * 1536;
  const float* l1 = rl + b * 24576 + y1l * 1536;
  float ga0 = g0[t], gb0 = g1[t];
  float ga1 = 0.0f, gb1 = 0.0f;
  if (t < 320) { ga1 = g0[t + 448]; gb1 = g1[t + 448]; }
  float la0 = l0[t], lb0 = l1[t];
  float la1 = l0[t + 448], lb1 = l1[t + 448];
  float la2 = l0[t + 896], lb2s = l1[t + 896];
  float la3 = 0.0f, lb3 = 0.0f;
  if (t < 192) { la3 = l0[t + 1344]; lb3 = l1[t + 1344]; }
  float sg0 = 0.0f, sg1 = 0.0f;
  if (t < 64) {
    const float* gbp = gsem + b * 4096;
    sg0 = gbp[y0s * 64 + t];
    sg1 = gbp[y1s * 64 + t];
  }
  sG[t] = ga0 * (1.0f - wyg) + gb0 * wyg;
  if (t < 320) sG[t + 448] = ga1 * (1.0f - wyg) + gb1 * wyg;
  sL[t] = la0 * (1.0f - wyl) + lb0 * wyl;
  sL[t + 448] = la1 * (1.0f - wyl) + lb1 * wyl;
  sL[t + 896] = la2 * (1.0f - wyl) + lb2s * wyl;
  if (t < 192) sL[t + 1344] = la3 * (1.0f - wyl) + lb3 * wyl;
  if (t < 64) sgr[t] = sg0 * (1.0f - wys) + sg1 * wys;
  __syncthreads();

  float rr_[2] = {rrA, rrB}, gg_[2] = {ggA, ggB}, bb_[2] = {bbA, bbB};
#pragma unroll
  for (int ip = 0; ip < 2; ++ip) {
    int w = ip * 448 + t;
    int hw = h * 896 + w;
    float r = rr_[ip];
    float g = gg_[ip];
    float bl = bb_[ip];
    float lr = srgb_lin(r), lg = srgb_lin(g), lb2 = srgb_lin(bl);
    float X = 0.412453f * lr + 0.357580f * lg + 0.180423f * lb2;
    float Y = 0.212671f * lr + 0.715160f * lg + 0.072169f * lb2;
    float Z = 0.019334f * lr + 0.119193f * lg + 0.950227f * lb2;
    float fx_ = labf(X * (1.0f / 0.950456f));
    float fy_ = labf(Y);
    float fz_ = labf(Z * (1.0f / 1.088754f));
    float gch = 0.50877193f * fy_ - 0.070175439f +
                1.0964912f * fabsf(fx_ - fy_) + 0.43859649f * fabsf(fy_ - fz_);
    gch = fminf(fmaxf(gch, 0.0f), 1.0f);
    float sx = fminf(fmaxf((w + 0.5f) * (1.0f / 14.0f) - 0.5f, 0.0f), 63.0f);
    int x0s = (int)sx;
    int x1s = x0s < 63 ? x0s + 1 : 63;
    float wxs = sx - (float)x0s;
    float gs = sgr[x0s] * (1.0f - wxs) + sgr[x1s] * wxs;
    float gg = 0.5f * gch + 0.5f * gs;
    __builtin_nontemporal_store(gg, &out[OUT_G + b * HWPIX + hw]);
    float fzc = fminf(fmaxf(gg * 7.0f, 0.0f), 7.0f);
    int z0 = (int)fzc;
    if (z0 > 7) z0 = 7;
    int z1 = z0 < 7 ? z0 + 1 : 7;
    float wz = fzc - (float)z0;
    float o0, o1, o2;
    slice_lds<8>(sG, w, z0, z1, wz, r, g, bl, o0, o1, o2);
    __builtin_nontemporal_store(o0, &out[(b * 3 + 0) * HWPIX + hw]);
    __builtin_nontemporal_store(o1, &out[(b * 3 + 1) * HWPIX + hw]);
    __builtin_nontemporal_store(o2, &out[(b * 3 + 2) * HWPIX + hw]);
    slice_lds<16>(sL, w, z0, z1, wz, r, g, bl, o0, o1, o2);
    __builtin_nontemporal_store(o0, &out[OUT_IL + (b * 3 + 0) * HWPIX + hw]);
    __builtin_nontemporal_store(o1, &out[OUT_IL + (b * 3 + 1) * HWPIX + hw]);
    __builtin_nontemporal_store(o2, &out[OUT_IL + (b * 3 + 2) * HWPIX + hw]);
  }
}

// ---------------------------------------------------------------------------
extern "C" void kernel_launch(void* const* d_in, const int* in_sizes, int n_in,
                              void* d_out, int out_size, void* d_ws,
                              size_t ws_size, hipStream_t stream) {
  const float* R = (const float*)d_in[0];
  const float* F = (const float*)d_in[1];
  const float* img = (const float*)d_in[2];
  const float* dino_w = (const float*)d_in[5];
  const float* dino_b = (const float*)d_in[6];
  const float* fus_w = (const float*)d_in[7];
  const float* fus_b = (const float*)d_in[8];
  const float* g1_w = (const float*)d_in[9];
  const float* g1_b = (const float*)d_in[10];
  const float* g2_w = (const float*)d_in[11];
  const float* g2_b = (const float*)d_in[12];
  const float* lw = (const float*)d_in[13];
  const float* lb = (const float*)d_in[14];
  const float* gw1 = (const float*)d_in[15];
  const float* gb1 = (const float*)d_in[16];
  const float* gw2 = (const float*)d_in[17];
  const float* gb2 = (const float*)d_in[18];
  float* out = (float*)d_out;
  float* ws = (float*)d_ws;

  float* Wt4 = ws + WS_WT4;
  float* bc = ws + WS_BC;
  float* pooled = ws + WS_POOL;
  float* gsem = ws + WS_GSEM;
  float* rg = ws + WS_RG;
  float* rl = ws + WS_RL;
  float* w1T = ws + WS_W1T;
  float* lwT = ws + WS_LWT;

  k_prep<<<643, 256, 0, stream>>>(fus_w, fus_b, dino_w, dino_b, gw1, lw,
                                  Wt4, bc, w1T, lwT);
  k_mid<<<768, 512, 0, stream>>>(R, F, Wt4, bc, lwT, lb,
                                 pooled, out + OUT_GL, rl,
                                 w1T, gb1, gw2, gb2, gsem);
  k_head<<<96, 1024, 0, stream>>>(pooled, g1_w, g1_b, g2_w, g2_b,
                                  out + OUT_GG, rg);
  k_pixel<<<3584, 448, 0, stream>>>(img, gsem, rg, rl, out);
}